// Round 1
// baseline (4561.187 us; speedup 1.0000x reference)
//
#include <hip/hip_runtime.h>
#include <hip/hip_bf16.h>

typedef __hip_bfloat16 bf16;
typedef short s8v __attribute__((ext_vector_type(8)));   // 8 bf16 payload for MFMA
typedef float f4v __attribute__((ext_vector_type(4)));   // MFMA accumulator

#define B_   32
#define L_   64
#define TENC 196
#define INP  2048
#define H_   512
#define V_   32000
#define NBLK 64    // persistent-kernel grid: 64 blocks, 1/CU, trivially co-resident

static __device__ __forceinline__ float sigf(float x) { return 1.0f / (1.0f + expf(-x)); }
static __device__ __forceinline__ short f2bs(float x) {
    bf16 h = (bf16)x;
    return *(short*)&h;
}
static __device__ __forceinline__ float b2f(short s) {
    return __uint_as_float(((unsigned int)(unsigned short)s) << 16);
}
static __device__ __forceinline__ float ldf(const void* p, size_t i, int f32) {
    if (f32) return ((const float*)p)[i];
    return (float)((const bf16*)p)[i];
}
static __device__ __forceinline__ s8v ld8(const void* p, size_t i, int f32) {
    if (f32) {
        const float* fp = (const float*)p + i;
        float4 a = *(const float4*)fp;
        float4 b = *(const float4*)(fp + 4);
        s8v r;
        r[0] = f2bs(a.x); r[1] = f2bs(a.y); r[2] = f2bs(a.z); r[3] = f2bs(a.w);
        r[4] = f2bs(b.x); r[5] = f2bs(b.y); r[6] = f2bs(b.z); r[7] = f2bs(b.w);
        return r;
    }
    return *(const s8v*)((const bf16*)p + i);
}
static __device__ __forceinline__ s8v ld8lo(const void* p, size_t i, int f32) {
    s8v r = {};
    if (f32) {
        const float* fp = (const float*)p + i;
        float4 a = *(const float4*)fp;
        float4 b = *(const float4*)(fp + 4);
        float v[8] = {a.x, a.y, a.z, a.w, b.x, b.y, b.z, b.w};
        for (int j = 0; j < 8; ++j) {
            bf16 hi = (bf16)v[j];
            bf16 lo = (bf16)(v[j] - (float)hi);
            r[j] = *(short*)&lo;
        }
    }
    return r;
}

// ---- device-coherent (agent-scope, sc0/sc1 => L2-bypassing) f32 access ----
// All cross-block recurrence state flows through these; therefore no
// buffer_wbl2 / buffer_inv fences are needed at the grid barrier.
static __device__ __forceinline__ float ldcoh(const float* p) {
    unsigned int u = __hip_atomic_load((unsigned int*)p, __ATOMIC_RELAXED, __HIP_MEMORY_SCOPE_AGENT);
    return __uint_as_float(u);
}
static __device__ __forceinline__ void stcoh(float* p, float v) {
    __hip_atomic_store((unsigned int*)p, __float_as_uint(v), __ATOMIC_RELAXED, __HIP_MEMORY_SCOPE_AGENT);
}

// fence-light grid barrier: vmcnt(0) drains this thread's sc1 stores to the
// coherence point; syncthreads orders the whole block before tid0 signals.
static __device__ __forceinline__ void gridbar(int* cnt, int target) {
    asm volatile("s_waitcnt vmcnt(0)" ::: "memory");
    __syncthreads();
    if (threadIdx.x == 0) {
        __hip_atomic_fetch_add(cnt, 1, __ATOMIC_RELAXED, __HIP_MEMORY_SCOPE_AGENT);
        while (__hip_atomic_load(cnt, __ATOMIC_RELAXED, __HIP_MEMORY_SCOPE_AGENT) < target)
            __builtin_amdgcn_s_sleep(1);
    }
    __syncthreads();
}

// ---------------- dtype detector ----------------
__global__ __launch_bounds__(256) void k_detect(const void* __restrict__ feat,
                                                int* __restrict__ flag) {
    __shared__ float red[256];
    const unsigned short* p = (const unsigned short*)feat;
    float mx = 0.f;
    for (int i = threadIdx.x; i < 65536; i += 256) {
        unsigned int u = ((unsigned int)p[i]) << 16;
        float v = __uint_as_float(u);
        mx = fmaxf(mx, fabsf(v));
    }
    red[threadIdx.x] = mx;
    __syncthreads();
    for (int s = 128; s; s >>= 1) {
        if (threadIdx.x < s) red[threadIdx.x] = fmaxf(red[threadIdx.x], red[threadIdx.x + s]);
        __syncthreads();
    }
    if (threadIdx.x == 0) flag[0] = (red[0] > 1e4f) ? 1 : 0;
}

// ---------------- pre-convert enc + LSTM weights to bf16; combine biases; init barrier
__global__ __launch_bounds__(256) void k_prep(const int* __restrict__ dflag,
                                              const void* __restrict__ enc,
                                              const void* __restrict__ w_ih0, const void* __restrict__ w_hh0,
                                              const void* __restrict__ w_ih1, const void* __restrict__ w_hh1,
                                              const void* __restrict__ b_ih0, const void* __restrict__ b_hh0,
                                              const void* __restrict__ b_ih1, const void* __restrict__ b_hh1,
                                              bf16* __restrict__ enc16,
                                              bf16* __restrict__ Wp0, bf16* __restrict__ Wp1,
                                              float* __restrict__ bias0, float* __restrict__ bias1,
                                              int* __restrict__ bar) {
    int f32 = *dflag;
    int gid = blockIdx.x * 256 + threadIdx.x;
    if (gid == 0) bar[0] = 0;
    const int GE = (B_ * TENC * H_) / 8;      // 401408
    const int GW = (2048 * 1024) / 8;         // 262144
    int stride = gridDim.x * 256;
    for (int g = gid; g < GE + 2 * GW; g += stride) {
        if (g < GE) {
            *(s8v*)(enc16 + (size_t)g * 8) = ld8(enc, (size_t)g * 8, f32);
        } else if (g < GE + GW) {
            int gg = g - GE; int j = gg >> 7; int k = (gg & 127) * 8;
            s8v v = (k < 512) ? ld8(w_ih0, (size_t)j * 1024 + 512 + k, f32)
                              : ld8(w_hh0, (size_t)j * 512 + (k - 512), f32);
            *(s8v*)(Wp0 + (size_t)j * 1024 + k) = v;
        } else {
            int gg = g - GE - GW; int j = gg >> 7; int k = (gg & 127) * 8;
            s8v v = (k < 512) ? ld8(w_ih1, (size_t)j * 512 + k, f32)
                              : ld8(w_hh1, (size_t)j * 512 + (k - 512), f32);
            *(s8v*)(Wp1 + (size_t)j * 1024 + k) = v;
        }
    }
    for (int j = gid; j < 2048; j += stride) {
        bias0[j] = ldf(b_ih0, j, f32) + ldf(b_hh0, j, f32);
        bias1[j] = ldf(b_ih1, j, f32) + ldf(b_hh1, j, f32);
    }
}

// ---------------- Gemb[t*32+b][j] = emb(hi/lo) @ w_ih0[:, 0:512]^T  (f32 out) --------
__global__ __launch_bounds__(256) void k_gemb(const int* __restrict__ dflag,
                                              const int* __restrict__ captions,
                                              const void* __restrict__ embed,
                                              const void* __restrict__ w_ih0,
                                              float* __restrict__ Gemb) {
    __shared__ short As[128][40];
    __shared__ short Bs[128][40];
    int f32 = *dflag;
    int n0 = blockIdx.x * 128;
    int m0 = blockIdx.y * 128;
    int tid = threadIdx.x, lane = tid & 63, wv = tid >> 6;
    int wm = wv >> 1, wn = wv & 1;
    f4v acc[16] = {};
    for (int k0 = 0; k0 < 512; k0 += 32) {
        for (int s = tid; s < 512; s += 256) {
            int r = s >> 2, cs = (s & 3) * 8;
            int R = m0 + r, e = R >> 1, part = R & 1;
            int b = e & 31, tt = e >> 5;
            size_t ei = (size_t)captions[b * L_ + tt] * H_ + k0 + cs;
            *(s8v*)&As[r][cs] = part ? ld8lo(embed, ei, f32) : ld8(embed, ei, f32);
        }
        for (int s = tid; s < 512; s += 256) {
            int r = s >> 2, cs = (s & 3) * 8;
            *(s8v*)&Bs[r][cs] = ld8(w_ih0, (size_t)(n0 + r) * 1024 + k0 + cs, f32);
        }
        __syncthreads();
        int kq = (lane >> 4) * 8;
        s8v af[4], bfv[4];
        for (int i = 0; i < 4; ++i) af[i]  = *(const s8v*)&As[wm * 64 + i * 16 + (lane & 15)][kq];
        for (int i = 0; i < 4; ++i) bfv[i] = *(const s8v*)&Bs[wn * 64 + i * 16 + (lane & 15)][kq];
        for (int mi = 0; mi < 4; ++mi)
            for (int ni = 0; ni < 4; ++ni)
                acc[mi * 4 + ni] = __builtin_amdgcn_mfma_f32_16x16x32_bf16(af[mi], bfv[ni], acc[mi * 4 + ni], 0, 0, 0);
        __syncthreads();
    }
    int n = lane & 15, quad = lane >> 4;
    for (int ni = 0; ni < 4; ++ni) {
        int col = n0 + wn * 64 + ni * 16 + n;
        for (int mi = 0; mi < 4; ++mi) {
            f4v a = acc[mi * 4 + ni];
            int rowbase = m0 + wm * 64 + mi * 16 + quad * 4;
            int e0 = rowbase >> 1;
            Gemb[(size_t)e0 * 2048 + col]       = a[0] + a[1];
            Gemb[(size_t)(e0 + 1) * 2048 + col] = a[2] + a[3];
        }
    }
}

// ---------------- feature MLP ----------------
__global__ __launch_bounds__(256) void k_feat1(const int* __restrict__ dflag,
                                               const void* __restrict__ feat,
                                               const void* __restrict__ w,
                                               const void* __restrict__ bias,
                                               float* __restrict__ t1) {
    int f32 = *dflag;
    int wid = (blockIdx.x * 256 + threadIdx.x) >> 6;
    int lane = threadIdx.x & 63;
    int b = wid >> 9, o = wid & 511;
    float acc = 0.f;
    for (int k = lane; k < INP; k += 64)
        acc += ldf(feat, (size_t)b * INP + k, f32) * ldf(w, (size_t)o * INP + k, f32);
    for (int off = 32; off; off >>= 1) acc += __shfl_down(acc, off, 64);
    if (lane == 0) {
        acc += ldf(bias, o, f32);
        t1[b * H_ + o] = acc > 0.f ? acc : 0.f;
    }
}

__global__ __launch_bounds__(256) void k_feat2(const int* __restrict__ dflag,
                                               const float* __restrict__ t1,
                                               const void* __restrict__ w,
                                               const void* __restrict__ bias,
                                               float* __restrict__ c0, float* __restrict__ c1,
                                               float* __restrict__ h0A, float* __restrict__ h1A) {
    int f32 = *dflag;
    int wid = (blockIdx.x * 256 + threadIdx.x) >> 6;
    int lane = threadIdx.x & 63;
    int b = wid >> 9, o = wid & 511;
    float acc = 0.f;
    for (int k = lane; k < H_; k += 64)
        acc += t1[b * H_ + k] * ldf(w, (size_t)o * H_ + k, f32);
    for (int off = 32; off; off >>= 1) acc += __shfl_down(acc, off, 64);
    if (lane == 0) {
        float v = acc + ldf(bias, o, f32);
        int idx = b * H_ + o;
        c0[idx] = v; c1[idx] = v;
        h0A[idx] = v; h1A[idx] = v;
    }
}

// ---- one LSTM-cell gate GEMM: C[64 hi/lo rows x 32 gate-rows], K=1024 in 2 halves.
// A-halves come from device-coherent f32 state (srcA0 = cols 0..511, srcA1 = 512..1023),
// split to bf16 hi/lo during LDS staging. Half-1 globals are register-prefetched so
// their latency hides under half-0's MFMA. Result sums land in ep[gate][unit][batch].
static __device__ __forceinline__ void cell_gemm(
        const float* __restrict__ srcA0, const float* __restrict__ srcA1,
        const bf16* __restrict__ Wp,
        int tid, int u0, int mrow, int kq, int nlo, int wv, int lane,
        short (*Asm)[520], short (*Wsm)[520], float (*ep)[8][32]) {
    f4v acc0 = {}, acc1 = {};
    float ta[64]; s8v wa[8];
    #pragma unroll
    for (int q = 0; q < 64; ++q) ta[q] = ldcoh(srcA0 + q * 256 + tid);
    #pragma unroll
    for (int q = 0; q < 8; ++q) {
        int s = q * 256 + tid; int r = s >> 6, cc = (s & 63) * 8;
        size_t j = (size_t)((r >> 3) * 512 + u0 + (r & 7));
        wa[q] = *(const s8v*)(Wp + j * 1024 + cc);
    }
    #pragma unroll
    for (int q = 0; q < 64; ++q) {
        int g = q * 256 + tid; int b = g >> 9, c = g & 511;
        float v = ta[q];
        bf16 hi = (bf16)v; bf16 lo = (bf16)(v - (float)hi);
        Asm[2 * b][c]     = *(short*)&hi;
        Asm[2 * b + 1][c] = *(short*)&lo;
    }
    #pragma unroll
    for (int q = 0; q < 8; ++q) {
        int s = q * 256 + tid; int r = s >> 6, cc = (s & 63) * 8;
        *(s8v*)&Wsm[r][cc] = wa[q];
    }
    // prefetch half 1 (consumed after half-0 MFMA; latency hidden)
    float tb[64]; s8v wb[8];
    #pragma unroll
    for (int q = 0; q < 64; ++q) tb[q] = ldcoh(srcA1 + q * 256 + tid);
    #pragma unroll
    for (int q = 0; q < 8; ++q) {
        int s = q * 256 + tid; int r = s >> 6, cc = (s & 63) * 8;
        size_t j = (size_t)((r >> 3) * 512 + u0 + (r & 7));
        wb[q] = *(const s8v*)(Wp + j * 1024 + 512 + cc);
    }
    __syncthreads();
    #pragma unroll
    for (int kk = 0; kk < 16; ++kk) {
        s8v a  = *(const s8v*)&Asm[mrow][kk * 32 + kq];
        s8v b0 = *(const s8v*)&Wsm[nlo][kk * 32 + kq];
        s8v b1 = *(const s8v*)&Wsm[16 + nlo][kk * 32 + kq];
        acc0 = __builtin_amdgcn_mfma_f32_16x16x32_bf16(a, b0, acc0, 0, 0, 0);
        acc1 = __builtin_amdgcn_mfma_f32_16x16x32_bf16(a, b1, acc1, 0, 0, 0);
    }
    __syncthreads();
    #pragma unroll
    for (int q = 0; q < 64; ++q) {
        int g = q * 256 + tid; int b = g >> 9, c = g & 511;
        float v = tb[q];
        bf16 hi = (bf16)v; bf16 lo = (bf16)(v - (float)hi);
        Asm[2 * b][c]     = *(short*)&hi;
        Asm[2 * b + 1][c] = *(short*)&lo;
    }
    #pragma unroll
    for (int q = 0; q < 8; ++q) {
        int s = q * 256 + tid; int r = s >> 6, cc = (s & 63) * 8;
        *(s8v*)&Wsm[r][cc] = wb[q];
    }
    __syncthreads();
    #pragma unroll
    for (int kk = 0; kk < 16; ++kk) {
        s8v a  = *(const s8v*)&Asm[mrow][kk * 32 + kq];
        s8v b0 = *(const s8v*)&Wsm[nlo][kk * 32 + kq];
        s8v b1 = *(const s8v*)&Wsm[16 + nlo][kk * 32 + kq];
        acc0 = __builtin_amdgcn_mfma_f32_16x16x32_bf16(a, b0, acc0, 0, 0, 0);
        acc1 = __builtin_amdgcn_mfma_f32_16x16x32_bf16(a, b1, acc1, 0, 0, 0);
    }
    int quad = lane >> 4;
    int b0i = wv * 8 + quad * 2;
    // acc0 -> Wsm rows 0..15 (gates 0,1), acc1 -> rows 16..31 (gates 2,3)
    ep[nlo >> 3][nlo & 7][b0i]           = acc0[0] + acc0[1];
    ep[nlo >> 3][nlo & 7][b0i + 1]       = acc0[2] + acc0[3];
    ep[2 + (nlo >> 3)][nlo & 7][b0i]     = acc1[0] + acc1[1];
    ep[2 + (nlo >> 3)][nlo & 7][b0i + 1] = acc1[2] + acc1[3];
    __syncthreads();
}

// ---------------- persistent recurrence kernel: 64 steps of att->cell0->cell1 --------
__global__ __launch_bounds__(256, 1) void k_recur(
        const bf16* __restrict__ enc16,
        const bf16* __restrict__ Wp0, const bf16* __restrict__ Wp1,
        const float* __restrict__ bias0, const float* __restrict__ bias1,
        const float* __restrict__ Gemb,
        const float* __restrict__ c0i, const float* __restrict__ c1i,
        float* __restrict__ h0A, float* __restrict__ h0B,
        float* __restrict__ h1A, float* __restrict__ h1B,
        float* __restrict__ ctxf,
        bf16* __restrict__ hs, int* __restrict__ bar) {
    __shared__ short Asm[64][520];     // 66.5 KB  (stride 520 shorts -> 4-bank row skew)
    __shared__ short Wsm[32][520];     // 33.3 KB
    __shared__ float qs[H_];
    __shared__ float sc[256];
    __shared__ float red[256];
    __shared__ float ep[4][8][32];
    const float SCALE = 0.04419417382415922f;
    int blk = blockIdx.x, tid = threadIdx.x;
    int lane = tid & 63, wv = tid >> 6;
    int u0 = blk * 8;                  // 8 hidden units per block, 64 blocks = 512
    int eb = tid & 31, eu = tid >> 5, ej = u0 + eu;   // epilogue (batch, unit)
    int mrow = wv * 16 + (lane & 15);
    int kq = (lane >> 4) * 8;
    int nlo = lane & 15;
    int nbar = 0;
    // cell state is block-private per (eb,ej): keep it in registers for all 64 steps
    float c0r = c0i[eb * H_ + ej];
    float c1r = c1i[eb * H_ + ej];
    float bi0 = bias0[ej], bf0 = bias0[512 + ej], bg0 = bias0[1024 + ej], bo0 = bias0[1536 + ej];
    float bi1 = bias1[ej], bf1 = bias1[512 + ej], bg1 = bias1[1024 + ej], bo1 = bias1[1536 + ej];

    for (int t = 0; t < L_; ++t) {
        int p = t & 1;
        const float* h0p = p ? h0B : h0A;  float* h0n = p ? h0A : h0B;
        const float* h1p = p ? h1B : h1A;  float* h1n = p ? h1A : h1B;

        // ---- Phase A: attention (blocks 0..31, one batch each) ----
        if (blk < 32) {
            int b = blk;
            for (int i = tid; i < H_; i += 256) qs[i] = ldcoh(h1p + b * H_ + i);
            __syncthreads();
            if (tid < TENC) {
                // one thread per tt: 512 independent FMAs, no shuffle reductions
                const bf16* erow = enc16 + ((size_t)b * TENC + tid) * H_;
                float a = 0.f;
                #pragma unroll 4
                for (int k = 0; k < H_; k += 8) {
                    s8v e8 = *(const s8v*)(erow + k);
                    float4 q0 = *(const float4*)&qs[k];
                    float4 q1 = *(const float4*)&qs[k + 4];
                    a += q0.x * b2f(e8[0]) + q0.y * b2f(e8[1])
                       + q0.z * b2f(e8[2]) + q0.w * b2f(e8[3])
                       + q1.x * b2f(e8[4]) + q1.y * b2f(e8[5])
                       + q1.z * b2f(e8[6]) + q1.w * b2f(e8[7]);
                }
                sc[tid] = a * SCALE;
            }
            __syncthreads();
            red[tid] = (tid < TENC) ? sc[tid] : -1e30f;
            __syncthreads();
            for (int s = 128; s; s >>= 1) { if (tid < s) red[tid] = fmaxf(red[tid], red[tid + s]); __syncthreads(); }
            float m = red[0];
            __syncthreads();
            float e = (tid < TENC) ? expf(sc[tid] - m) : 0.f;
            red[tid] = e;
            __syncthreads();
            for (int s = 128; s; s >>= 1) { if (tid < s) red[tid] += red[tid + s]; __syncthreads(); }
            float inv = 1.0f / red[0];
            __syncthreads();
            if (tid < TENC) sc[tid] = e * inv;
            __syncthreads();
            int j0 = tid * 2;
            float a0 = 0.f, a1 = 0.f;
            const bf16* ebase = enc16 + (size_t)b * TENC * H_ + j0;
            for (int tt = 0; tt < TENC; ++tt) {
                unsigned int u = *(const unsigned int*)(ebase + (size_t)tt * H_);
                float pr = sc[tt];
                a0 += pr * __uint_as_float((u & 0xffffu) << 16);
                a1 += pr * __uint_as_float(u & 0xffff0000u);
            }
            stcoh(ctxf + b * H_ + j0, a0);
            stcoh(ctxf + b * H_ + j0 + 1, a1);
        }
        ++nbar; gridbar(bar, nbar * NBLK);

        // ---- Phase B: cell0  (A = [ctx ; h0prev], W = Wp0, + Gemb + bias0) ----
        {
            size_t ge = (size_t)(t * 32 + eb) * 2048 + ej;   // prefetch emb-gates
            float g0 = Gemb[ge], g1 = Gemb[ge + 512], g2 = Gemb[ge + 1024], g3 = Gemb[ge + 1536];
            cell_gemm(ctxf, h0p, Wp0, tid, u0, mrow, kq, nlo, wv, lane, Asm, Wsm, ep);
            float gi = ep[0][eu][eb] + bi0 + g0;
            float gf = ep[1][eu][eb] + bf0 + g1;
            float gg = ep[2][eu][eb] + bg0 + g2;
            float go = ep[3][eu][eb] + bo0 + g3;
            float c2 = sigf(gf) * c0r + sigf(gi) * tanhf(gg);
            float h2 = sigf(go) * tanhf(c2);
            c0r = c2;
            stcoh(h0n + eb * H_ + ej, h2);
        }
        ++nbar; gridbar(bar, nbar * NBLK);

        // ---- Phase C: cell1  (A = [h0new ; h1prev], W = Wp1, + bias1) ----
        {
            cell_gemm(h0n, h1p, Wp1, tid, u0, mrow, kq, nlo, wv, lane, Asm, Wsm, ep);
            float gi = ep[0][eu][eb] + bi1;
            float gf = ep[1][eu][eb] + bf1;
            float gg = ep[2][eu][eb] + bg1;
            float go = ep[3][eu][eb] + bo1;
            float c2 = sigf(gf) * c1r + sigf(gi) * tanhf(gg);
            float h2 = sigf(go) * tanhf(c2);
            c1r = c2;
            stcoh(h1n + eb * H_ + ej, h2);
            hs[(size_t)(t * 32 + eb) * H_ + ej] = (bf16)h2;   // cross-kernel: normal store
        }
        ++nbar; gridbar(bar, nbar * NBLK);
    }
}

// ---------------- vocab projection (grid transposed: m fastest for fcw reuse) -------
__global__ __launch_bounds__(256) void k_vocab(const int* __restrict__ dflag,
                                               const bf16* __restrict__ hs,
                                               const void* __restrict__ fcw,
                                               const void* __restrict__ fcb,
                                               void* __restrict__ out) {
    __shared__ short As[128][40];
    __shared__ short Bs[128][40];
    int f32 = *dflag;
    int m0 = blockIdx.x * 128;
    int n0 = blockIdx.y * 128;
    int tid = threadIdx.x, lane = tid & 63, wv = tid >> 6;
    int wm = wv >> 1, wn = wv & 1;
    f4v acc[16] = {};
    for (int k0 = 0; k0 < 512; k0 += 32) {
        for (int s = tid; s < 512; s += 256) {
            int r = s >> 2, cs = (s & 3) * 8;
            *(s8v*)&As[r][cs] = *(const s8v*)(hs + (size_t)(m0 + r) * 512 + k0 + cs);
        }
        for (int s = tid; s < 512; s += 256) {
            int r = s >> 2, cs = (s & 3) * 8;
            *(s8v*)&Bs[r][cs] = ld8(fcw, (size_t)(n0 + r) * 512 + k0 + cs, f32);
        }
        __syncthreads();
        int kq = (lane >> 4) * 8;
        s8v af[4], bfv[4];
        for (int i = 0; i < 4; ++i) af[i]  = *(const s8v*)&As[wm * 64 + i * 16 + (lane & 15)][kq];
        for (int i = 0; i < 4; ++i) bfv[i] = *(const s8v*)&Bs[wn * 64 + i * 16 + (lane & 15)][kq];
        for (int mi = 0; mi < 4; ++mi)
            for (int ni = 0; ni < 4; ++ni)
                acc[mi * 4 + ni] = __builtin_amdgcn_mfma_f32_16x16x32_bf16(af[mi], bfv[ni], acc[mi * 4 + ni], 0, 0, 0);
        __syncthreads();
    }
    int n = lane & 15, quad = lane >> 4;
    for (int ni = 0; ni < 4; ++ni) {
        int col = n0 + wn * 64 + ni * 16 + n;
        float bias = ldf(fcb, col, f32);
        for (int mi = 0; mi < 4; ++mi) {
            f4v a = acc[mi * 4 + ni];
            for (int rg = 0; rg < 4; ++rg) {
                int row = m0 + wm * 64 + mi * 16 + quad * 4 + rg;
                float v = a[rg] + bias;
                if (f32) ((float*)out)[(size_t)row * V_ + col] = v;
                else     ((bf16*)out)[(size_t)row * V_ + col] = (bf16)v;
            }
        }
    }
}

extern "C" void kernel_launch(void* const* d_in, const int* in_sizes, int n_in,
                              void* d_out, int out_size, void* d_ws, size_t ws_size,
                              hipStream_t stream) {
    const void* features = d_in[0];
    const int*  captions = (const int*)d_in[1];
    const void* enc      = d_in[3];
    const void* embed    = d_in[4];
    const void* ft1w     = d_in[5];
    const void* ft1b     = d_in[6];
    const void* ft2w     = d_in[7];
    const void* ft2b     = d_in[8];
    const void* w_ih0    = d_in[9];
    const void* w_hh0    = d_in[10];
    const void* b_ih0    = d_in[11];
    const void* b_hh0    = d_in[12];
    const void* w_ih1    = d_in[13];
    const void* w_hh1    = d_in[14];
    const void* b_ih1    = d_in[15];
    const void* b_hh1    = d_in[16];
    const void* fcw      = d_in[17];
    const void* fcb      = d_in[18];

    char* ws = (char*)d_ws;
    size_t off = 0;
    float* t1    = (float*)(ws + off); off += 32 * 512 * 4;
    float* c0    = (float*)(ws + off); off += 32 * 512 * 4;
    float* c1    = (float*)(ws + off); off += 32 * 512 * 4;
    float* h0A   = (float*)(ws + off); off += 32 * 512 * 4;
    float* h0B   = (float*)(ws + off); off += 32 * 512 * 4;
    float* h1A   = (float*)(ws + off); off += 32 * 512 * 4;
    float* h1B   = (float*)(ws + off); off += 32 * 512 * 4;
    float* ctxf  = (float*)(ws + off); off += 32 * 512 * 4;
    bf16* hs     = (bf16*)(ws + off); off += (size_t)2048 * 512 * 2;
    bf16* enc16  = (bf16*)(ws + off); off += (size_t)32 * 196 * 512 * 2;
    bf16* Wp0    = (bf16*)(ws + off); off += (size_t)2048 * 1024 * 2;
    bf16* Wp1    = (bf16*)(ws + off); off += (size_t)2048 * 1024 * 2;
    float* bias0 = (float*)(ws + off); off += 2048 * 4;
    float* bias1 = (float*)(ws + off); off += 2048 * 4;
    float* Gemb  = (float*)(ws + off); off += (size_t)2048 * 2048 * 4;
    int* dflag   = (int*)(ws + off); off += 16;
    int* bar     = (int*)(ws + off); off += 16;

    k_detect<<<1, 256, 0, stream>>>(features, dflag);
    k_prep<<<1024, 256, 0, stream>>>(dflag, enc, w_ih0, w_hh0, w_ih1, w_hh1,
                                     b_ih0, b_hh0, b_ih1, b_hh1,
                                     enc16, Wp0, Wp1, bias0, bias1, bar);
    k_gemb<<<dim3(16, 32), 256, 0, stream>>>(dflag, captions, embed, w_ih0, Gemb);
    k_feat1<<<4096, 256, 0, stream>>>(dflag, features, ft1w, ft1b, t1);
    k_feat2<<<4096, 256, 0, stream>>>(dflag, t1, ft2w, ft2b, c0, c1, h0A, h1A);
    k_recur<<<NBLK, 256, 0, stream>>>(enc16, Wp0, Wp1, bias0, bias1, Gemb,
                                      c0, c1, h0A, h0B, h1A, h1B, ctxf, hs, bar);
    k_vocab<<<dim3(16, 250), 256, 0, stream>>>(dflag, hs, fcw, fcb, (void*)d_out);
}

// Round 2
// 2807.829 us; speedup vs baseline: 1.6245x; 1.6245x over previous
//
#include <hip/hip_runtime.h>
#include <hip/hip_bf16.h>

typedef __hip_bfloat16 bf16;
typedef short s8v __attribute__((ext_vector_type(8)));   // 8 bf16 payload for MFMA
typedef float f4v __attribute__((ext_vector_type(4)));   // MFMA accumulator
typedef unsigned long long u64;
typedef unsigned int u32;

#define B_   32
#define L_   64
#define TENC 196
#define INP  2048
#define H_   512
#define V_   32000
#define NBLK 128   // persistent grid: 128 blocks, 1/CU (LDS-bound), co-resident

static __device__ __forceinline__ float sigf(float x) { return 1.0f / (1.0f + expf(-x)); }
static __device__ __forceinline__ short f2bs(float x) {
    bf16 h = (bf16)x;
    return *(short*)&h;
}
static __device__ __forceinline__ float b2f(short s) {
    return __uint_as_float(((unsigned int)(unsigned short)s) << 16);
}
// pack f32 -> (hi bf16 << 16) | lo bf16   (hi+lo reconstructs ~f32 precision)
static __device__ __forceinline__ u32 packhl(float v) {
    bf16 hi = (bf16)v;
    float r = v - (float)hi;
    bf16 lo = (bf16)r;
    return ((u32)(*(unsigned short*)&hi) << 16) | (u32)(*(unsigned short*)&lo);
}
static __device__ __forceinline__ float ldf(const void* p, size_t i, int f32) {
    if (f32) return ((const float*)p)[i];
    return (float)((const bf16*)p)[i];
}
static __device__ __forceinline__ s8v ld8(const void* p, size_t i, int f32) {
    if (f32) {
        const float* fp = (const float*)p + i;
        float4 a = *(const float4*)fp;
        float4 b = *(const float4*)(fp + 4);
        s8v r;
        r[0] = f2bs(a.x); r[1] = f2bs(a.y); r[2] = f2bs(a.z); r[3] = f2bs(a.w);
        r[4] = f2bs(b.x); r[5] = f2bs(b.y); r[6] = f2bs(b.z); r[7] = f2bs(b.w);
        return r;
    }
    return *(const s8v*)((const bf16*)p + i);
}
static __device__ __forceinline__ s8v ld8lo(const void* p, size_t i, int f32) {
    s8v r = {};
    if (f32) {
        const float* fp = (const float*)p + i;
        float4 a = *(const float4*)fp;
        float4 b = *(const float4*)(fp + 4);
        float v[8] = {a.x, a.y, a.z, a.w, b.x, b.y, b.z, b.w};
        for (int j = 0; j < 8; ++j) {
            bf16 hi = (bf16)v[j];
            bf16 lo = (bf16)(v[j] - (float)hi);
            r[j] = *(short*)&lo;
        }
    }
    return r;
}

// ---- device-coherent (agent-scope) access: all cross-block state goes through
// these, so the grid barrier needs no L2 writeback/invalidate fences.
static __device__ __forceinline__ u64 ld64coh(const void* p) {
    return __hip_atomic_load((const u64*)p, __ATOMIC_RELAXED, __HIP_MEMORY_SCOPE_AGENT);
}
static __device__ __forceinline__ void st32coh(u32* p, u32 v) {
    __hip_atomic_store(p, v, __ATOMIC_RELAXED, __HIP_MEMORY_SCOPE_AGENT);
}
static __device__ __forceinline__ void st64coh(u32* p, u64 v) {
    __hip_atomic_store((u64*)p, v, __ATOMIC_RELAXED, __HIP_MEMORY_SCOPE_AGENT);
}

// fence-light grid barrier: vmcnt(0) drains this wave's coherent stores,
// syncthreads orders the block, tid0 signals + polls (proven in round 1).
static __device__ __forceinline__ void gridbar(int* cnt, int target) {
    asm volatile("s_waitcnt vmcnt(0)" ::: "memory");
    __syncthreads();
    if (threadIdx.x == 0) {
        __hip_atomic_fetch_add(cnt, 1, __ATOMIC_RELAXED, __HIP_MEMORY_SCOPE_AGENT);
        while (__hip_atomic_load(cnt, __ATOMIC_RELAXED, __HIP_MEMORY_SCOPE_AGENT) < target)
            __builtin_amdgcn_s_sleep(1);
    }
    __syncthreads();
}

// issue 32 coherent 8B loads: per-thread 64 packed-u32 elems of one K-half
// chunk q: b = 2q + (tid>>7), k = (tid&127)*4  -> [b][k..k+3]
static __device__ __forceinline__ void issue32(const u32* St, int tid, u64* f) {
    int b0 = (tid >> 7), k = (tid & 127) * 4;
    #pragma unroll
    for (int q = 0; q < 16; ++q) {
        const u32* s = St + (2 * q + b0) * H_ + k;
        f[2 * q]     = ld64coh(s);
        f[2 * q + 1] = ld64coh(s + 2);
    }
}
// unpack hi/lo and write the K-half into Asm (hi row 2b, lo row 2b+1)
static __device__ __forceinline__ void stage_write(const u64* f, int tid, short (*A)[520]) {
    int b0 = (tid >> 7), k = (tid & 127) * 4;
    #pragma unroll
    for (int q = 0; q < 16; ++q) {
        u32 v0 = (u32)f[2 * q],     v1 = (u32)(f[2 * q] >> 32);
        u32 v2 = (u32)f[2 * q + 1], v3 = (u32)(f[2 * q + 1] >> 32);
        int b = 2 * q + b0;
        uint2 hi, lo;
        hi.x = (v0 >> 16) | (v1 & 0xffff0000u);
        hi.y = (v2 >> 16) | (v3 & 0xffff0000u);
        lo.x = (v0 & 0xffffu) | (v1 << 16);
        lo.y = (v2 & 0xffffu) | (v3 << 16);
        *(uint2*)&A[2 * b][k]     = hi;
        *(uint2*)&A[2 * b + 1][k] = lo;
    }
}
// one K-half of the cell GEMM: A[64 rows] x W[16 gate-rows], K=512
static __device__ __forceinline__ f4v mfma_half(const short (*W)[1048], const short (*A)[520],
                                                int mrow, int nlo, int kq, int koff, f4v acc) {
    #pragma unroll
    for (int kk = 0; kk < 16; ++kk) {
        s8v a = *(const s8v*)&A[mrow][kk * 32 + kq];
        s8v b = *(const s8v*)&W[nlo][koff + kk * 32 + kq];
        acc = __builtin_amdgcn_mfma_f32_16x16x32_bf16(a, b, acc, 0, 0, 0);
    }
    return acc;
}

// ---------------- dtype detector ----------------
__global__ __launch_bounds__(256) void k_detect(const void* __restrict__ feat,
                                                int* __restrict__ flag) {
    __shared__ float red[256];
    const unsigned short* p = (const unsigned short*)feat;
    float mx = 0.f;
    for (int i = threadIdx.x; i < 65536; i += 256) {
        unsigned int u = ((unsigned int)p[i]) << 16;
        float v = __uint_as_float(u);
        mx = fmaxf(mx, fabsf(v));
    }
    red[threadIdx.x] = mx;
    __syncthreads();
    for (int s = 128; s; s >>= 1) {
        if (threadIdx.x < s) red[threadIdx.x] = fmaxf(red[threadIdx.x], red[threadIdx.x + s]);
        __syncthreads();
    }
    if (threadIdx.x == 0) flag[0] = (red[0] > 1e4f) ? 1 : 0;
}

// ---------------- pre-convert enc + LSTM weights to bf16; combine biases; init barrier
__global__ __launch_bounds__(256) void k_prep(const int* __restrict__ dflag,
                                              const void* __restrict__ enc,
                                              const void* __restrict__ w_ih0, const void* __restrict__ w_hh0,
                                              const void* __restrict__ w_ih1, const void* __restrict__ w_hh1,
                                              const void* __restrict__ b_ih0, const void* __restrict__ b_hh0,
                                              const void* __restrict__ b_ih1, const void* __restrict__ b_hh1,
                                              bf16* __restrict__ enc16,
                                              bf16* __restrict__ Wp0, bf16* __restrict__ Wp1,
                                              float* __restrict__ bias0, float* __restrict__ bias1,
                                              int* __restrict__ bar) {
    int f32 = *dflag;
    int gid = blockIdx.x * 256 + threadIdx.x;
    if (gid == 0) bar[0] = 0;
    const int GE = (B_ * TENC * H_) / 8;      // 401408
    const int GW = (2048 * 1024) / 8;         // 262144
    int stride = gridDim.x * 256;
    for (int g = gid; g < GE + 2 * GW; g += stride) {
        if (g < GE) {
            *(s8v*)(enc16 + (size_t)g * 8) = ld8(enc, (size_t)g * 8, f32);
        } else if (g < GE + GW) {
            int gg = g - GE; int j = gg >> 7; int k = (gg & 127) * 8;
            s8v v = (k < 512) ? ld8(w_ih0, (size_t)j * 1024 + 512 + k, f32)
                              : ld8(w_hh0, (size_t)j * 512 + (k - 512), f32);
            *(s8v*)(Wp0 + (size_t)j * 1024 + k) = v;
        } else {
            int gg = g - GE - GW; int j = gg >> 7; int k = (gg & 127) * 8;
            s8v v = (k < 512) ? ld8(w_ih1, (size_t)j * 512 + k, f32)
                              : ld8(w_hh1, (size_t)j * 512 + (k - 512), f32);
            *(s8v*)(Wp1 + (size_t)j * 1024 + k) = v;
        }
    }
    for (int j = gid; j < 2048; j += stride) {
        bias0[j] = ldf(b_ih0, j, f32) + ldf(b_hh0, j, f32);
        bias1[j] = ldf(b_ih1, j, f32) + ldf(b_hh1, j, f32);
    }
}

// ---------------- Gemb[t*32+b][j] = emb(hi/lo) @ w_ih0[:, 0:512]^T  (f32 out) --------
__global__ __launch_bounds__(256) void k_gemb(const int* __restrict__ dflag,
                                              const int* __restrict__ captions,
                                              const void* __restrict__ embed,
                                              const void* __restrict__ w_ih0,
                                              float* __restrict__ Gemb) {
    __shared__ short As[128][40];
    __shared__ short Bs[128][40];
    int f32 = *dflag;
    int n0 = blockIdx.x * 128;
    int m0 = blockIdx.y * 128;
    int tid = threadIdx.x, lane = tid & 63, wv = tid >> 6;
    int wm = wv >> 1, wn = wv & 1;
    f4v acc[16] = {};
    for (int k0 = 0; k0 < 512; k0 += 32) {
        for (int s = tid; s < 512; s += 256) {
            int r = s >> 2, cs = (s & 3) * 8;
            int R = m0 + r, e = R >> 1, part = R & 1;
            int b = e & 31, tt = e >> 5;
            size_t ei = (size_t)captions[b * L_ + tt] * H_ + k0 + cs;
            *(s8v*)&As[r][cs] = part ? ld8lo(embed, ei, f32) : ld8(embed, ei, f32);
        }
        for (int s = tid; s < 512; s += 256) {
            int r = s >> 2, cs = (s & 3) * 8;
            *(s8v*)&Bs[r][cs] = ld8(w_ih0, (size_t)(n0 + r) * 1024 + k0 + cs, f32);
        }
        __syncthreads();
        int kq = (lane >> 4) * 8;
        s8v af[4], bfv[4];
        for (int i = 0; i < 4; ++i) af[i]  = *(const s8v*)&As[wm * 64 + i * 16 + (lane & 15)][kq];
        for (int i = 0; i < 4; ++i) bfv[i] = *(const s8v*)&Bs[wn * 64 + i * 16 + (lane & 15)][kq];
        for (int mi = 0; mi < 4; ++mi)
            for (int ni = 0; ni < 4; ++ni)
                acc[mi * 4 + ni] = __builtin_amdgcn_mfma_f32_16x16x32_bf16(af[mi], bfv[ni], acc[mi * 4 + ni], 0, 0, 0);
        __syncthreads();
    }
    int n = lane & 15, quad = lane >> 4;
    for (int ni = 0; ni < 4; ++ni) {
        int col = n0 + wn * 64 + ni * 16 + n;
        for (int mi = 0; mi < 4; ++mi) {
            f4v a = acc[mi * 4 + ni];
            int rowbase = m0 + wm * 64 + mi * 16 + quad * 4;
            int e0 = rowbase >> 1;
            Gemb[(size_t)e0 * 2048 + col]       = a[0] + a[1];
            Gemb[(size_t)(e0 + 1) * 2048 + col] = a[2] + a[3];
        }
    }
}

// ---------------- feature MLP ----------------
__global__ __launch_bounds__(256) void k_feat1(const int* __restrict__ dflag,
                                               const void* __restrict__ feat,
                                               const void* __restrict__ w,
                                               const void* __restrict__ bias,
                                               float* __restrict__ t1) {
    int f32 = *dflag;
    int wid = (blockIdx.x * 256 + threadIdx.x) >> 6;
    int lane = threadIdx.x & 63;
    int b = wid >> 9, o = wid & 511;
    float acc = 0.f;
    for (int k = lane; k < INP; k += 64)
        acc += ldf(feat, (size_t)b * INP + k, f32) * ldf(w, (size_t)o * INP + k, f32);
    for (int off = 32; off; off >>= 1) acc += __shfl_down(acc, off, 64);
    if (lane == 0) {
        acc += ldf(bias, o, f32);
        t1[b * H_ + o] = acc > 0.f ? acc : 0.f;
    }
}

__global__ __launch_bounds__(256) void k_feat2(const int* __restrict__ dflag,
                                               const float* __restrict__ t1,
                                               const void* __restrict__ w,
                                               const void* __restrict__ bias,
                                               float* __restrict__ c0, float* __restrict__ c1,
                                               u32* __restrict__ h0A, u32* __restrict__ h1A) {
    int f32 = *dflag;
    int wid = (blockIdx.x * 256 + threadIdx.x) >> 6;
    int lane = threadIdx.x & 63;
    int b = wid >> 9, o = wid & 511;
    float acc = 0.f;
    for (int k = lane; k < H_; k += 64)
        acc += t1[b * H_ + k] * ldf(w, (size_t)o * H_ + k, f32);
    for (int off = 32; off; off >>= 1) acc += __shfl_down(acc, off, 64);
    if (lane == 0) {
        float v = acc + ldf(bias, o, f32);
        int idx = b * H_ + o;
        c0[idx] = v; c1[idx] = v;
        u32 pk = packhl(v);
        h0A[idx] = pk; h1A[idx] = pk;
    }
}

// ---------------- persistent recurrence kernel ----------------
// 128 blocks x 4 units. Weights LDS-resident. Per step:
//   A: [blk<32: attention]  + all: stage h0prev-half, MFMA (accB) | bar
//   B: stage ctx-half, MFMA, epilogue0 -> h0new; stage h1prev-half, MFMA (accC) | bar
//   C: stage h0new-half, MFMA, epilogue1 -> h1new, hs | bar
__global__ __launch_bounds__(256, 1) void k_recur(
        const bf16* __restrict__ enc16,
        const bf16* __restrict__ Wp0, const bf16* __restrict__ Wp1,
        const float* __restrict__ bias0, const float* __restrict__ bias1,
        const float* __restrict__ Gemb,
        const float* __restrict__ c0i, const float* __restrict__ c1i,
        u32* __restrict__ h0A, u32* __restrict__ h0B,
        u32* __restrict__ h1A, u32* __restrict__ h1B,
        u32* __restrict__ ctxp,
        bf16* __restrict__ hs, int* __restrict__ bar) {
    __shared__ short Asm[64][520];        // 66.5 KB: A-half [32b x hi/lo][512k]
    __shared__ short Wsm[2][16][1048];    // 67.1 KB: resident weights, 2 cells
    __shared__ float qs[H_];
    __shared__ float sc[256];
    __shared__ float wred[8];
    __shared__ float ep[4][4][32];
    const float SCALE = 0.04419417382415922f;
    int blk = blockIdx.x, tid = threadIdx.x;
    int lane = tid & 63, wv = tid >> 6;
    int u0 = blk * 4;                      // 4 hidden units per block
    int mrow = wv * 16 + (lane & 15);
    int kq = (lane >> 4) * 8;
    int nlo = lane & 15;
    int quad = lane >> 4;
    int b0i = wv * 8 + quad * 2;
    int eb = tid & 31, eu = (tid >> 5) & 3, ej = u0 + eu;
    int epi = tid < 128;

    // resident weight load (once)
    for (int cell = 0; cell < 2; ++cell) {
        const bf16* Wp = cell ? Wp1 : Wp0;
        for (int s = tid; s < 2048; s += 256) {
            int r = s >> 7, cc = (s & 127) * 8;
            size_t j = (size_t)((r >> 2) * H_ + u0 + (r & 3));
            *(s8v*)&Wsm[cell][r][cc] = *(const s8v*)(Wp + j * 1024 + cc);
        }
    }
    float c0r = 0.f, c1r = 0.f;
    float bi0 = 0, bf0 = 0, bg0 = 0, bo0 = 0, bi1 = 0, bf1 = 0, bg1 = 0, bo1 = 0;
    if (epi) {
        c0r = c0i[eb * H_ + ej]; c1r = c1i[eb * H_ + ej];
        bi0 = bias0[ej]; bf0 = bias0[512 + ej]; bg0 = bias0[1024 + ej]; bo0 = bias0[1536 + ej];
        bi1 = bias1[ej]; bf1 = bias1[512 + ej]; bg1 = bias1[1024 + ej]; bo1 = bias1[1536 + ej];
    }
    __syncthreads();
    int nbar = 0;

    for (int t = 0; t < L_; ++t) {
        int p = t & 1;
        const u32* h0p = p ? h0B : h0A;  u32* h0n = p ? h0A : h0B;
        const u32* h1p = p ? h1B : h1A;  u32* h1n = p ? h1A : h1B;

        // ===== Phase A: attention (blk<32) + pre-barrier h0prev half of cell0 =====
        u64 fA[32];
        issue32(h0p, tid, fA);
        f4v accB = {};
        if (blk < B_) {
            int b = blk;
            {
                u64 v = ld64coh(h1p + b * H_ + 2 * tid);
                u32 v0 = (u32)v, v1 = (u32)(v >> 32);
                qs[2 * tid]     = b2f((short)(v0 >> 16)) + b2f((short)(v0 & 0xffffu));
                qs[2 * tid + 1] = b2f((short)(v1 >> 16)) + b2f((short)(v1 & 0xffffu));
            }
            __syncthreads();
            if (tid < TENC) {
                const bf16* erow = enc16 + ((size_t)b * TENC + tid) * H_;
                float a0 = 0, a1 = 0, a2 = 0, a3 = 0, a4 = 0, a5 = 0, a6 = 0, a7 = 0;
                #pragma unroll 4
                for (int k = 0; k < H_; k += 8) {
                    s8v e8 = *(const s8v*)(erow + k);
                    float4 q0 = *(const float4*)&qs[k];
                    float4 q1 = *(const float4*)&qs[k + 4];
                    a0 += q0.x * b2f(e8[0]); a1 += q0.y * b2f(e8[1]);
                    a2 += q0.z * b2f(e8[2]); a3 += q0.w * b2f(e8[3]);
                    a4 += q1.x * b2f(e8[4]); a5 += q1.y * b2f(e8[5]);
                    a6 += q1.z * b2f(e8[6]); a7 += q1.w * b2f(e8[7]);
                }
                sc[tid] = (((a0 + a1) + (a2 + a3)) + ((a4 + a5) + (a6 + a7))) * SCALE;
            }
            __syncthreads();
            float v = (tid < TENC) ? sc[tid] : -1e30f;
            float m = v;
            #pragma unroll
            for (int off = 32; off; off >>= 1) m = fmaxf(m, __shfl_xor(m, off, 64));
            if (lane == 0) wred[wv] = m;
            __syncthreads();
            m = fmaxf(fmaxf(wred[0], wred[1]), fmaxf(wred[2], wred[3]));
            float e = (tid < TENC) ? expf(v - m) : 0.f;
            float s = e;
            #pragma unroll
            for (int off = 32; off; off >>= 1) s += __shfl_xor(s, off, 64);
            if (lane == 0) wred[4 + wv] = s;
            __syncthreads();
            float inv = 1.0f / ((wred[4] + wred[5]) + (wred[6] + wred[7]));
            if (tid < TENC) sc[tid] = e * inv;
            __syncthreads();
            // ctx: thread owns cols 2tid, 2tid+1
            const bf16* ebase = enc16 + (size_t)b * TENC * H_ + 2 * tid;
            float x0 = 0, x1 = 0, y0 = 0, y1 = 0;
            #pragma unroll 4
            for (int tt = 0; tt < TENC; tt += 2) {
                u32 ua = *(const u32*)(ebase + (size_t)tt * H_);
                u32 ub = *(const u32*)(ebase + (size_t)(tt + 1) * H_);
                float p0 = sc[tt], p1 = sc[tt + 1];
                x0 += p0 * b2f((short)ua); x1 += p0 * b2f((short)(ua >> 16));
                y0 += p1 * b2f((short)ub); y1 += p1 * b2f((short)(ub >> 16));
            }
            u64 pk = ((u64)packhl(x1 + y1) << 32) | (u64)packhl(x0 + y0);
            st64coh(ctxp + b * H_ + 2 * tid, pk);
        }
        stage_write(fA, tid, Asm);                 // h0prev -> K-half
        __syncthreads();
        accB = mfma_half(Wsm[0], Asm, mrow, nlo, kq, 512, accB);
        ++nbar; gridbar(bar, nbar * NBLK);

        // ===== Phase B: ctx half of cell0 + epilogue0; then h1prev half of cell1 =====
        {
            u64 fB[32];
            issue32(ctxp, tid, fB);                // fresh (just produced)
            float g0 = 0, g1 = 0, g2 = 0, g3 = 0;
            if (epi) {
                size_t ge = (size_t)(t * 32 + eb) * 2048 + ej;
                g0 = Gemb[ge]; g1 = Gemb[ge + 512]; g2 = Gemb[ge + 1024]; g3 = Gemb[ge + 1536];
            }
            u64 fC[32];
            issue32(h1p, tid, fC);                 // prefetch for cell1's old half
            stage_write(fB, tid, Asm);
            __syncthreads();
            accB = mfma_half(Wsm[0], Asm, mrow, nlo, kq, 0, accB);
            ep[nlo >> 2][nlo & 3][b0i]     = accB[0] + accB[1];
            ep[nlo >> 2][nlo & 3][b0i + 1] = accB[2] + accB[3];
            __syncthreads();
            if (epi) {
                float gi = ep[0][eu][eb] + bi0 + g0;
                float gf = ep[1][eu][eb] + bf0 + g1;
                float gg = ep[2][eu][eb] + bg0 + g2;
                float go = ep[3][eu][eb] + bo0 + g3;
                float c2 = sigf(gf) * c0r + sigf(gi) * tanhf(gg);
                float h2 = sigf(go) * tanhf(c2);
                c0r = c2;
                st32coh(h0n + eb * H_ + ej, packhl(h2));
            }
            stage_write(fC, tid, Asm);             // h1prev -> K-half (Asm free post-MFMA+sync)
            __syncthreads();
            f4v accC = {};
            accC = mfma_half(Wsm[1], Asm, mrow, nlo, kq, 512, accC);
            ++nbar; gridbar(bar, nbar * NBLK);

            // ===== Phase C: h0new half of cell1 + epilogue1 =====
            u64 fD[32];
            issue32(h0n, tid, fD);
            stage_write(fD, tid, Asm);
            __syncthreads();
            accC = mfma_half(Wsm[1], Asm, mrow, nlo, kq, 0, accC);
            ep[nlo >> 2][nlo & 3][b0i]     = accC[0] + accC[1];
            ep[nlo >> 2][nlo & 3][b0i + 1] = accC[2] + accC[3];
            __syncthreads();
            if (epi) {
                float gi = ep[0][eu][eb] + bi1;
                float gf = ep[1][eu][eb] + bf1;
                float gg = ep[2][eu][eb] + bg1;
                float go = ep[3][eu][eb] + bo1;
                float c2 = sigf(gf) * c1r + sigf(gi) * tanhf(gg);
                float h2 = sigf(go) * tanhf(c2);
                c1r = c2;
                st32coh(h1n + eb * H_ + ej, packhl(h2));
                hs[(size_t)(t * 32 + eb) * H_ + ej] = (bf16)h2;
            }
            ++nbar; gridbar(bar, nbar * NBLK);
        }
    }
}

// ---------------- vocab projection (grid transposed: m fastest for fcw reuse) -------
__global__ __launch_bounds__(256) void k_vocab(const int* __restrict__ dflag,
                                               const bf16* __restrict__ hs,
                                               const void* __restrict__ fcw,
                                               const void* __restrict__ fcb,
                                               void* __restrict__ out) {
    __shared__ short As[128][40];
    __shared__ short Bs[128][40];
    int f32 = *dflag;
    int m0 = blockIdx.x * 128;
    int n0 = blockIdx.y * 128;
    int tid = threadIdx.x, lane = tid & 63, wv = tid >> 6;
    int wm = wv >> 1, wn = wv & 1;
    f4v acc[16] = {};
    for (int k0 = 0; k0 < 512; k0 += 32) {
        for (int s = tid; s < 512; s += 256) {
            int r = s >> 2, cs = (s & 3) * 8;
            *(s8v*)&As[r][cs] = *(const s8v*)(hs + (size_t)(m0 + r) * 512 + k0 + cs);
        }
        for (int s = tid; s < 512; s += 256) {
            int r = s >> 2, cs = (s & 3) * 8;
            *(s8v*)&Bs[r][cs] = ld8(fcw, (size_t)(n0 + r) * 512 + k0 + cs, f32);
        }
        __syncthreads();
        int kq = (lane >> 4) * 8;
        s8v af[4], bfv[4];
        for (int i = 0; i < 4; ++i) af[i]  = *(const s8v*)&As[wm * 64 + i * 16 + (lane & 15)][kq];
        for (int i = 0; i < 4; ++i) bfv[i] = *(const s8v*)&Bs[wn * 64 + i * 16 + (lane & 15)][kq];
        for (int mi = 0; mi < 4; ++mi)
            for (int ni = 0; ni < 4; ++ni)
                acc[mi * 4 + ni] = __builtin_amdgcn_mfma_f32_16x16x32_bf16(af[mi], bfv[ni], acc[mi * 4 + ni], 0, 0, 0);
        __syncthreads();
    }
    int n = lane & 15, quad = lane >> 4;
    for (int ni = 0; ni < 4; ++ni) {
        int col = n0 + wn * 64 + ni * 16 + n;
        float bias = ldf(fcb, col, f32);
        for (int mi = 0; mi < 4; ++mi) {
            f4v a = acc[mi * 4 + ni];
            for (int rg = 0; rg < 4; ++rg) {
                int row = m0 + wm * 64 + mi * 16 + quad * 4 + rg;
                float v = a[rg] + bias;
                if (f32) ((float*)out)[(size_t)row * V_ + col] = v;
                else     ((bf16*)out)[(size_t)row * V_ + col] = (bf16)v;
            }
        }
    }
}

extern "C" void kernel_launch(void* const* d_in, const int* in_sizes, int n_in,
                              void* d_out, int out_size, void* d_ws, size_t ws_size,
                              hipStream_t stream) {
    const void* features = d_in[0];
    const int*  captions = (const int*)d_in[1];
    const void* enc      = d_in[3];
    const void* embed    = d_in[4];
    const void* ft1w     = d_in[5];
    const void* ft1b     = d_in[6];
    const void* ft2w     = d_in[7];
    const void* ft2b     = d_in[8];
    const void* w_ih0    = d_in[9];
    const void* w_hh0    = d_in[10];
    const void* b_ih0    = d_in[11];
    const void* b_hh0    = d_in[12];
    const void* w_ih1    = d_in[13];
    const void* w_hh1    = d_in[14];
    const void* b_ih1    = d_in[15];
    const void* b_hh1    = d_in[16];
    const void* fcw      = d_in[17];
    const void* fcb      = d_in[18];

    char* ws = (char*)d_ws;
    size_t off = 0;
    float* t1    = (float*)(ws + off); off += 32 * 512 * 4;
    float* c0    = (float*)(ws + off); off += 32 * 512 * 4;
    float* c1    = (float*)(ws + off); off += 32 * 512 * 4;
    u32* h0A     = (u32*)(ws + off); off += 32 * 512 * 4;
    u32* h0B     = (u32*)(ws + off); off += 32 * 512 * 4;
    u32* h1A     = (u32*)(ws + off); off += 32 * 512 * 4;
    u32* h1B     = (u32*)(ws + off); off += 32 * 512 * 4;
    u32* ctxp    = (u32*)(ws + off); off += 32 * 512 * 4;
    bf16* hs     = (bf16*)(ws + off); off += (size_t)2048 * 512 * 2;
    bf16* enc16  = (bf16*)(ws + off); off += (size_t)32 * 196 * 512 * 2;
    bf16* Wp0    = (bf16*)(ws + off); off += (size_t)2048 * 1024 * 2;
    bf16* Wp1    = (bf16*)(ws + off); off += (size_t)2048 * 1024 * 2;
    float* bias0 = (float*)(ws + off); off += 2048 * 4;
    float* bias1 = (float*)(ws + off); off += 2048 * 4;
    float* Gemb  = (float*)(ws + off); off += (size_t)2048 * 2048 * 4;
    int* dflag   = (int*)(ws + off); off += 16;
    int* bar     = (int*)(ws + off); off += 16;

    k_detect<<<1, 256, 0, stream>>>(features, dflag);
    k_prep<<<1024, 256, 0, stream>>>(dflag, enc, w_ih0, w_hh0, w_ih1, w_hh1,
                                     b_ih0, b_hh0, b_ih1, b_hh1,
                                     enc16, Wp0, Wp1, bias0, bias1, bar);
    k_gemb<<<dim3(16, 32), 256, 0, stream>>>(dflag, captions, embed, w_ih0, Gemb);
    k_feat1<<<4096, 256, 0, stream>>>(dflag, features, ft1w, ft1b, t1);
    k_feat2<<<4096, 256, 0, stream>>>(dflag, t1, ft2w, ft2b, c0, c1, h0A, h1A);
    k_recur<<<NBLK, 256, 0, stream>>>(enc16, Wp0, Wp1, bias0, bias1, Gemb,
                                      c0, c1, h0A, h0B, h1A, h1B, ctxp, hs, bar);
    k_vocab<<<dim3(16, 250), 256, 0, stream>>>(dflag, hs, fcw, fcb, (void*)d_out);
}

// Round 4
// 2635.588 us; speedup vs baseline: 1.7306x; 1.0654x over previous
//
#include <hip/hip_runtime.h>
#include <hip/hip_bf16.h>

typedef __hip_bfloat16 bf16;
typedef short s8v __attribute__((ext_vector_type(8)));   // 8 bf16 payload for MFMA
typedef float f4v __attribute__((ext_vector_type(4)));   // MFMA accumulator
typedef unsigned long long u64;
typedef unsigned int u32;

#define B_   32
#define L_   64
#define TENC 196
#define INP  2048
#define H_   512
#define V_   32000
#define NBLK 128   // persistent grid: 128 blocks, 1/CU (LDS-bound), co-resident
#define SLOTSTRIDE 16   // u32s => 64B per slot, one cacheline per block

static __device__ __forceinline__ float sigf(float x) { return 1.0f / (1.0f + expf(-x)); }
static __device__ __forceinline__ short f2bs(float x) {
    bf16 h = (bf16)x;
    return *(short*)&h;
}
static __device__ __forceinline__ float b2f(short s) {
    return __uint_as_float(((unsigned int)(unsigned short)s) << 16);
}
// pack f32 -> (hi bf16 << 16) | lo bf16   (hi+lo reconstructs ~f32 precision)
static __device__ __forceinline__ u32 packhl(float v) {
    bf16 hi = (bf16)v;
    float r = v - (float)hi;
    bf16 lo = (bf16)r;
    return ((u32)(*(unsigned short*)&hi) << 16) | (u32)(*(unsigned short*)&lo);
}
static __device__ __forceinline__ float ldf(const void* p, size_t i, int f32) {
    if (f32) return ((const float*)p)[i];
    return (float)((const bf16*)p)[i];
}
static __device__ __forceinline__ s8v ld8(const void* p, size_t i, int f32) {
    if (f32) {
        const float* fp = (const float*)p + i;
        float4 a = *(const float4*)fp;
        float4 b = *(const float4*)(fp + 4);
        s8v r;
        r[0] = f2bs(a.x); r[1] = f2bs(a.y); r[2] = f2bs(a.z); r[3] = f2bs(a.w);
        r[4] = f2bs(b.x); r[5] = f2bs(b.y); r[6] = f2bs(b.z); r[7] = f2bs(b.w);
        return r;
    }
    return *(const s8v*)((const bf16*)p + i);
}
static __device__ __forceinline__ s8v ld8lo(const void* p, size_t i, int f32) {
    s8v r = {};
    if (f32) {
        const float* fp = (const float*)p + i;
        float4 a = *(const float4*)fp;
        float4 b = *(const float4*)(fp + 4);
        float v[8] = {a.x, a.y, a.z, a.w, b.x, b.y, b.z, b.w};
        for (int j = 0; j < 8; ++j) {
            bf16 hi = (bf16)v[j];
            bf16 lo = (bf16)(v[j] - (float)hi);
            r[j] = *(short*)&lo;
        }
    }
    return r;
}

// ---- device-coherent (agent-scope) access: all cross-block state goes through
// these, so the grid barrier needs no L2 writeback/invalidate fences.
static __device__ __forceinline__ u64 ld64coh(const void* p) {
    return __hip_atomic_load((const u64*)p, __ATOMIC_RELAXED, __HIP_MEMORY_SCOPE_AGENT);
}
static __device__ __forceinline__ void st32coh(u32* p, u32 v) {
    __hip_atomic_store(p, v, __ATOMIC_RELAXED, __HIP_MEMORY_SCOPE_AGENT);
}
static __device__ __forceinline__ void st64coh(u32* p, u64 v) {
    __hip_atomic_store((u64*)p, v, __ATOMIC_RELAXED, __HIP_MEMORY_SCOPE_AGENT);
}

// ---- store-slot grid barrier: arrival = ONE relaxed store to a private slot
// (no RMW contention: 128 arrivals land in parallel). Wait = 128 threads poll
// one slot each + __syncthreads_and. Values are monotone (no reset).
// vmcnt(0)+syncthreads before the flag store drains every wave's coherent
// data stores to the coherence point first (proven ordering from round 1).
static __device__ __forceinline__ void slot_arrive(u32* slots, int blk, u32 val) {
    asm volatile("s_waitcnt vmcnt(0)" ::: "memory");
    __syncthreads();
    if (threadIdx.x == 0)
        __hip_atomic_store(slots + blk * SLOTSTRIDE, val, __ATOMIC_RELAXED, __HIP_MEMORY_SCOPE_AGENT);
}
static __device__ __forceinline__ void slot_wait(const u32* slots, int nslots, u32 val) {
    int tid = threadIdx.x;
    for (;;) {
        u32 v = val;
        if (tid < nslots)
            v = __hip_atomic_load(slots + tid * SLOTSTRIDE, __ATOMIC_RELAXED, __HIP_MEMORY_SCOPE_AGENT);
        if (__syncthreads_and((int)(v >= val))) break;
        __builtin_amdgcn_s_sleep(1);
    }
}

// issue 32 coherent 8B loads: per-thread 64 packed-u32 elems of one K-half
// chunk q: b = 2q + (tid>>7), k = (tid&127)*4  -> [b][k..k+3]
static __device__ __forceinline__ void issue32(const u32* St, int tid, u64* f) {
    int b0 = (tid >> 7), k = (tid & 127) * 4;
    #pragma unroll
    for (int q = 0; q < 16; ++q) {
        const u32* s = St + (2 * q + b0) * H_ + k;
        f[2 * q]     = ld64coh(s);
        f[2 * q + 1] = ld64coh(s + 2);
    }
}
// unpack hi/lo and write the K-half into Asm (hi row 2b, lo row 2b+1)
static __device__ __forceinline__ void stage_write(const u64* f, int tid, short (*A)[520]) {
    int b0 = (tid >> 7), k = (tid & 127) * 4;
    #pragma unroll
    for (int q = 0; q < 16; ++q) {
        u32 v0 = (u32)f[2 * q],     v1 = (u32)(f[2 * q] >> 32);
        u32 v2 = (u32)f[2 * q + 1], v3 = (u32)(f[2 * q + 1] >> 32);
        int b = 2 * q + b0;
        uint2 hi, lo;
        hi.x = (v0 >> 16) | (v1 & 0xffff0000u);
        hi.y = (v2 >> 16) | (v3 & 0xffff0000u);
        lo.x = (v0 & 0xffffu) | (v1 << 16);
        lo.y = (v2 & 0xffffu) | (v3 << 16);
        *(uint2*)&A[2 * b][k]     = hi;
        *(uint2*)&A[2 * b + 1][k] = lo;
    }
}
// one K-half of the cell GEMM: A[64 rows] x W[16 gate-rows], K=512
static __device__ __forceinline__ f4v mfma_half(const short (*W)[1048], const short (*A)[520],
                                                int mrow, int nlo, int kq, int koff, f4v acc) {
    #pragma unroll
    for (int kk = 0; kk < 16; ++kk) {
        s8v a = *(const s8v*)&A[mrow][kk * 32 + kq];
        s8v b = *(const s8v*)&W[nlo][koff + kk * 32 + kq];
        acc = __builtin_amdgcn_mfma_f32_16x16x32_bf16(a, b, acc, 0, 0, 0);
    }
    return acc;
}

// ---------------- dtype detector ----------------
__global__ __launch_bounds__(256) void k_detect(const void* __restrict__ feat,
                                                int* __restrict__ flag) {
    __shared__ float red[256];
    const unsigned short* p = (const unsigned short*)feat;
    float mx = 0.f;
    for (int i = threadIdx.x; i < 65536; i += 256) {
        unsigned int u = ((unsigned int)p[i]) << 16;
        float v = __uint_as_float(u);
        mx = fmaxf(mx, fabsf(v));
    }
    red[threadIdx.x] = mx;
    __syncthreads();
    for (int s = 128; s; s >>= 1) {
        if (threadIdx.x < s) red[threadIdx.x] = fmaxf(red[threadIdx.x], red[threadIdx.x + s]);
        __syncthreads();
    }
    if (threadIdx.x == 0) flag[0] = (red[0] > 1e4f) ? 1 : 0;
}

// ---------------- pre-convert enc + LSTM weights to bf16; combine biases; zero slots
__global__ __launch_bounds__(256) void k_prep(const int* __restrict__ dflag,
                                              const void* __restrict__ enc,
                                              const void* __restrict__ w_ih0, const void* __restrict__ w_hh0,
                                              const void* __restrict__ w_ih1, const void* __restrict__ w_hh1,
                                              const void* __restrict__ b_ih0, const void* __restrict__ b_hh0,
                                              const void* __restrict__ b_ih1, const void* __restrict__ b_hh1,
                                              bf16* __restrict__ enc16,
                                              bf16* __restrict__ Wp0, bf16* __restrict__ Wp1,
                                              float* __restrict__ bias0, float* __restrict__ bias1,
                                              u32* __restrict__ slots) {
    int f32 = *dflag;
    int gid = blockIdx.x * 256 + threadIdx.x;
    if (gid < NBLK * SLOTSTRIDE) slots[gid] = 0;
    const int GE = (B_ * TENC * H_) / 8;      // 401408
    const int GW = (2048 * 1024) / 8;         // 262144
    int stride = gridDim.x * 256;
    for (int g = gid; g < GE + 2 * GW; g += stride) {
        if (g < GE) {
            *(s8v*)(enc16 + (size_t)g * 8) = ld8(enc, (size_t)g * 8, f32);
        } else if (g < GE + GW) {
            int gg = g - GE; int j = gg >> 7; int k = (gg & 127) * 8;
            s8v v = (k < 512) ? ld8(w_ih0, (size_t)j * 1024 + 512 + k, f32)
                              : ld8(w_hh0, (size_t)j * 512 + (k - 512), f32);
            *(s8v*)(Wp0 + (size_t)j * 1024 + k) = v;
        } else {
            int gg = g - GE - GW; int j = gg >> 7; int k = (gg & 127) * 8;
            s8v v = (k < 512) ? ld8(w_ih1, (size_t)j * 512 + k, f32)
                              : ld8(w_hh1, (size_t)j * 512 + (k - 512), f32);
            *(s8v*)(Wp1 + (size_t)j * 1024 + k) = v;
        }
    }
    for (int j = gid; j < 2048; j += stride) {
        bias0[j] = ldf(b_ih0, j, f32) + ldf(b_hh0, j, f32);
        bias1[j] = ldf(b_ih1, j, f32) + ldf(b_hh1, j, f32);
    }
}

// ---------------- Gemb[t*32+b][j] = emb(hi/lo) @ w_ih0[:, 0:512]^T  (f32 out) --------
__global__ __launch_bounds__(256) void k_gemb(const int* __restrict__ dflag,
                                              const int* __restrict__ captions,
                                              const void* __restrict__ embed,
                                              const void* __restrict__ w_ih0,
                                              float* __restrict__ Gemb) {
    __shared__ short As[128][40];
    __shared__ short Bs[128][40];
    int f32 = *dflag;
    int n0 = blockIdx.x * 128;
    int m0 = blockIdx.y * 128;
    int tid = threadIdx.x, lane = tid & 63, wv = tid >> 6;
    int wm = wv >> 1, wn = wv & 1;
    f4v acc[16] = {};
    for (int k0 = 0; k0 < 512; k0 += 32) {
        for (int s = tid; s < 512; s += 256) {
            int r = s >> 2, cs = (s & 3) * 8;
            int R = m0 + r, e = R >> 1, part = R & 1;
            int b = e & 31, tt = e >> 5;
            size_t ei = (size_t)captions[b * L_ + tt] * H_ + k0 + cs;
            *(s8v*)&As[r][cs] = part ? ld8lo(embed, ei, f32) : ld8(embed, ei, f32);
        }
        for (int s = tid; s < 512; s += 256) {
            int r = s >> 2, cs = (s & 3) * 8;
            *(s8v*)&Bs[r][cs] = ld8(w_ih0, (size_t)(n0 + r) * 1024 + k0 + cs, f32);
        }
        __syncthreads();
        int kq = (lane >> 4) * 8;
        s8v af[4], bfv[4];
        for (int i = 0; i < 4; ++i) af[i]  = *(const s8v*)&As[wm * 64 + i * 16 + (lane & 15)][kq];
        for (int i = 0; i < 4; ++i) bfv[i] = *(const s8v*)&Bs[wn * 64 + i * 16 + (lane & 15)][kq];
        for (int mi = 0; mi < 4; ++mi)
            for (int ni = 0; ni < 4; ++ni)
                acc[mi * 4 + ni] = __builtin_amdgcn_mfma_f32_16x16x32_bf16(af[mi], bfv[ni], acc[mi * 4 + ni], 0, 0, 0);
        __syncthreads();
    }
    int n = lane & 15, quad = lane >> 4;
    for (int ni = 0; ni < 4; ++ni) {
        int col = n0 + wn * 64 + ni * 16 + n;
        for (int mi = 0; mi < 4; ++mi) {
            f4v a = acc[mi * 4 + ni];
            int rowbase = m0 + wm * 64 + mi * 16 + quad * 4;
            int e0 = rowbase >> 1;
            Gemb[(size_t)e0 * 2048 + col]       = a[0] + a[1];
            Gemb[(size_t)(e0 + 1) * 2048 + col] = a[2] + a[3];
        }
    }
}

// ---------------- feature MLP ----------------
__global__ __launch_bounds__(256) void k_feat1(const int* __restrict__ dflag,
                                               const void* __restrict__ feat,
                                               const void* __restrict__ w,
                                               const void* __restrict__ bias,
                                               float* __restrict__ t1) {
    int f32 = *dflag;
    int wid = (blockIdx.x * 256 + threadIdx.x) >> 6;
    int lane = threadIdx.x & 63;
    int b = wid >> 9, o = wid & 511;
    float acc = 0.f;
    for (int k = lane; k < INP; k += 64)
        acc += ldf(feat, (size_t)b * INP + k, f32) * ldf(w, (size_t)o * INP + k, f32);
    for (int off = 32; off; off >>= 1) acc += __shfl_down(acc, off, 64);
    if (lane == 0) {
        acc += ldf(bias, o, f32);
        t1[b * H_ + o] = acc > 0.f ? acc : 0.f;
    }
}

__global__ __launch_bounds__(256) void k_feat2(const int* __restrict__ dflag,
                                               const float* __restrict__ t1,
                                               const void* __restrict__ w,
                                               const void* __restrict__ bias,
                                               float* __restrict__ c0, float* __restrict__ c1,
                                               u32* __restrict__ h0A, u32* __restrict__ h1A) {
    int f32 = *dflag;
    int wid = (blockIdx.x * 256 + threadIdx.x) >> 6;
    int lane = threadIdx.x & 63;
    int b = wid >> 9, o = wid & 511;
    float acc = 0.f;
    for (int k = lane; k < H_; k += 64)
        acc += t1[b * H_ + k] * ldf(w, (size_t)o * H_ + k, f32);
    for (int off = 32; off; off >>= 1) acc += __shfl_down(acc, off, 64);
    if (lane == 0) {
        float v = acc + ldf(bias, o, f32);
        int idx = b * H_ + o;
        c0[idx] = v; c1[idx] = v;
        u32 pk = packhl(v);
        h0A[idx] = pk; h1A[idx] = pk;
    }
}

// ---------------- persistent recurrence kernel ----------------
// 128 blocks x 4 units. Weights LDS-resident. Per step:
//   A: [blk<32: attention]  + all: stage h0prev-half, MFMA (accB) | barA (32 producers)
//   B: stage ctx-half, MFMA, epilogue0 -> h0new; stage h1prev-half, MFMA (accC) | barB (full)
//   C: stage h0new-half, MFMA, epilogue1 -> h1new, hs | barC (full)
__global__ __launch_bounds__(256, 1) void k_recur(
        const bf16* __restrict__ enc16,
        const bf16* __restrict__ Wp0, const bf16* __restrict__ Wp1,
        const float* __restrict__ bias0, const float* __restrict__ bias1,
        const float* __restrict__ Gemb,
        const float* __restrict__ c0i, const float* __restrict__ c1i,
        u32* __restrict__ h0A, u32* __restrict__ h0B,
        u32* __restrict__ h1A, u32* __restrict__ h1B,
        u32* __restrict__ ctxp,
        bf16* __restrict__ hs, u32* __restrict__ slots) {
    __shared__ short Asm[64][520];        // 66.5 KB: A-half [32b x hi/lo][512k]
    __shared__ short Wsm[2][16][1048];    // 67.1 KB: resident weights, 2 cells
    __shared__ float qs[H_];
    __shared__ float sc[256];
    __shared__ float wred[8];
    __shared__ float ep[4][4][32];
    const float SCALE = 0.04419417382415922f;
    int blk = blockIdx.x, tid = threadIdx.x;
    int lane = tid & 63, wv = tid >> 6;
    int u0 = blk * 4;                      // 4 hidden units per block
    int mrow = wv * 16 + (lane & 15);
    int kq = (lane >> 4) * 8;
    int nlo = lane & 15;
    int quad = lane >> 4;
    int b0i = wv * 8 + quad * 2;
    int eb = tid & 31, eu = (tid >> 5) & 3, ej = u0 + eu;
    int epi = tid < 128;

    // resident weight load (once)
    for (int cell = 0; cell < 2; ++cell) {
        const bf16* Wp = cell ? Wp1 : Wp0;
        for (int s = tid; s < 2048; s += 256) {
            int r = s >> 7, cc = (s & 127) * 8;
            size_t j = (size_t)((r >> 2) * H_ + u0 + (r & 3));
            *(s8v*)&Wsm[cell][r][cc] = *(const s8v*)(Wp + j * 1024 + cc);
        }
    }
    float c0r = 0.f, c1r = 0.f;
    float bi0 = 0, bf0 = 0, bg0 = 0, bo0 = 0, bi1 = 0, bf1 = 0, bg1 = 0, bo1 = 0;
    if (epi) {
        c0r = c0i[eb * H_ + ej]; c1r = c1i[eb * H_ + ej];
        bi0 = bias0[ej]; bf0 = bias0[512 + ej]; bg0 = bias0[1024 + ej]; bo0 = bias0[1536 + ej];
        bi1 = bias1[ej]; bf1 = bias1[512 + ej]; bg1 = bias1[1024 + ej]; bo1 = bias1[1536 + ej];
    }
    __syncthreads();
    u32 nbar = 0;

    for (int t = 0; t < L_; ++t) {
        int p = t & 1;
        const u32* h0p = p ? h0B : h0A;  u32* h0n = p ? h0A : h0B;
        const u32* h1p = p ? h1B : h1A;  u32* h1n = p ? h1A : h1B;

        // ===== Phase A: attention (blk<32) + pre-barrier h0prev half of cell0 =====
        u64 fA[32];
        issue32(h0p, tid, fA);
        f4v accB = {};
        if (blk < B_) {
            int b = blk;
            {
                u64 v = ld64coh(h1p + b * H_ + 2 * tid);
                u32 v0 = (u32)v, v1 = (u32)(v >> 32);
                qs[2 * tid]     = b2f((short)(v0 >> 16)) + b2f((short)(v0 & 0xffffu));
                qs[2 * tid + 1] = b2f((short)(v1 >> 16)) + b2f((short)(v1 & 0xffffu));
            }
            __syncthreads();
            if (tid < TENC) {
                const bf16* erow = enc16 + ((size_t)b * TENC + tid) * H_;
                float a0 = 0, a1 = 0, a2 = 0, a3 = 0, a4 = 0, a5 = 0, a6 = 0, a7 = 0;
                #pragma unroll 4
                for (int k = 0; k < H_; k += 8) {
                    s8v e8 = *(const s8v*)(erow + k);
                    float4 q0 = *(const float4*)&qs[k];
                    float4 q1 = *(const float4*)&qs[k + 4];
                    a0 += q0.x * b2f(e8[0]); a1 += q0.y * b2f(e8[1]);
                    a2 += q0.z * b2f(e8[2]); a3 += q0.w * b2f(e8[3]);
                    a4 += q1.x * b2f(e8[4]); a5 += q1.y * b2f(e8[5]);
                    a6 += q1.z * b2f(e8[6]); a7 += q1.w * b2f(e8[7]);
                }
                sc[tid] = (((a0 + a1) + (a2 + a3)) + ((a4 + a5) + (a6 + a7))) * SCALE;
            }
            __syncthreads();
            float v = (tid < TENC) ? sc[tid] : -1e30f;
            float m = v;
            #pragma unroll
            for (int off = 32; off; off >>= 1) m = fmaxf(m, __shfl_xor(m, off, 64));
            if (lane == 0) wred[wv] = m;
            __syncthreads();
            m = fmaxf(fmaxf(wred[0], wred[1]), fmaxf(wred[2], wred[3]));
            float e = (tid < TENC) ? expf(v - m) : 0.f;
            float s = e;
            #pragma unroll
            for (int off = 32; off; off >>= 1) s += __shfl_xor(s, off, 64);
            if (lane == 0) wred[4 + wv] = s;
            __syncthreads();
            float inv = 1.0f / ((wred[4] + wred[5]) + (wred[6] + wred[7]));
            if (tid < TENC) sc[tid] = e * inv;
            __syncthreads();
            // ctx: thread owns cols 2tid, 2tid+1
            const bf16* ebase = enc16 + (size_t)b * TENC * H_ + 2 * tid;
            float x0 = 0, x1 = 0, y0 = 0, y1 = 0;
            #pragma unroll 4
            for (int tt = 0; tt < TENC; tt += 2) {
                u32 ua = *(const u32*)(ebase + (size_t)tt * H_);
                u32 ub = *(const u32*)(ebase + (size_t)(tt + 1) * H_);
                float p0 = sc[tt], p1 = sc[tt + 1];
                x0 += p0 * b2f((short)ua); x1 += p0 * b2f((short)(ua >> 16));
                y0 += p1 * b2f((short)ub); y1 += p1 * b2f((short)(ub >> 16));
            }
            u64 pk = ((u64)packhl(x1 + y1) << 32) | (u64)packhl(x0 + y0);
            st64coh(ctxp + b * H_ + 2 * tid, pk);
        }
        stage_write(fA, tid, Asm);                 // h0prev -> K-half
        __syncthreads();
        accB = mfma_half(Wsm[0], Asm, mrow, nlo, kq, 512, accB);
        ++nbar;
        if (blk < B_) slot_arrive(slots, blk, nbar);   // only attention blocks produce
        slot_wait(slots, B_, nbar);

        // ===== Phase B: ctx half of cell0 + epilogue0; then h1prev half of cell1 =====
        {
            u64 fB[32];
            issue32(ctxp, tid, fB);                // fresh (just produced)
            float g0 = 0, g1 = 0, g2 = 0, g3 = 0;
            if (epi) {
                size_t ge = (size_t)(t * 32 + eb) * 2048 + ej;
                g0 = Gemb[ge]; g1 = Gemb[ge + 512]; g2 = Gemb[ge + 1024]; g3 = Gemb[ge + 1536];
            }
            u64 fC[32];
            issue32(h1p, tid, fC);                 // prefetch for cell1's old half
            stage_write(fB, tid, Asm);
            __syncthreads();
            accB = mfma_half(Wsm[0], Asm, mrow, nlo, kq, 0, accB);
            ep[nlo >> 2][nlo & 3][b0i]     = accB[0] + accB[1];
            ep[nlo >> 2][nlo & 3][b0i + 1] = accB[2] + accB[3];
            __syncthreads();
            if (epi) {
                float gi = ep[0][eu][eb] + bi0 + g0;
                float gf = ep[1][eu][eb] + bf0 + g1;
                float gg = ep[2][eu][eb] + bg0 + g2;
                float go = ep[3][eu][eb] + bo0 + g3;
                float c2 = sigf(gf) * c0r + sigf(gi) * tanhf(gg);
                float h2 = sigf(go) * tanhf(c2);
                c0r = c2;
                st32coh(h0n + eb * H_ + ej, packhl(h2));
            }
            stage_write(fC, tid, Asm);             // h1prev -> K-half (Asm free post-MFMA+sync)
            __syncthreads();
            f4v accC = {};
            accC = mfma_half(Wsm[1], Asm, mrow, nlo, kq, 512, accC);
            ++nbar;
            slot_arrive(slots, blk, nbar);
            slot_wait(slots, NBLK, nbar);

            // ===== Phase C: h0new half of cell1 + epilogue1 =====
            u64 fD[32];
            issue32(h0n, tid, fD);
            stage_write(fD, tid, Asm);
            __syncthreads();
            accC = mfma_half(Wsm[1], Asm, mrow, nlo, kq, 0, accC);
            ep[nlo >> 2][nlo & 3][b0i]     = accC[0] + accC[1];
            ep[nlo >> 2][nlo & 3][b0i + 1] = accC[2] + accC[3];
            __syncthreads();
            if (epi) {
                float gi = ep[0][eu][eb] + bi1;
                float gf = ep[1][eu][eb] + bf1;
                float gg = ep[2][eu][eb] + bg1;
                float go = ep[3][eu][eb] + bo1;
                float c2 = sigf(gf) * c1r + sigf(gi) * tanhf(gg);
                float h2 = sigf(go) * tanhf(c2);
                c1r = c2;
                st32coh(h1n + eb * H_ + ej, packhl(h2));
                hs[(size_t)(t * 32 + eb) * H_ + ej] = (bf16)h2;
            }
            ++nbar;
            slot_arrive(slots, blk, nbar);
            slot_wait(slots, NBLK, nbar);
        }
    }
}

// ---------------- vocab projection (grid transposed: m fastest for fcw reuse) -------
__global__ __launch_bounds__(256) void k_vocab(const int* __restrict__ dflag,
                                               const bf16* __restrict__ hs,
                                               const void* __restrict__ fcw,
                                               const void* __restrict__ fcb,
                                               void* __restrict__ out) {
    __shared__ short As[128][40];
    __shared__ short Bs[128][40];
    int f32 = *dflag;
    int m0 = blockIdx.x * 128;
    int n0 = blockIdx.y * 128;
    int tid = threadIdx.x, lane = tid & 63, wv = tid >> 6;
    int wm = wv >> 1, wn = wv & 1;
    f4v acc[16] = {};
    for (int k0 = 0; k0 < 512; k0 += 32) {
        for (int s = tid; s < 512; s += 256) {
            int r = s >> 2, cs = (s & 3) * 8;
            *(s8v*)&As[r][cs] = *(const s8v*)(hs + (size_t)(m0 + r) * 512 + k0 + cs);
        }
        for (int s = tid; s < 512; s += 256) {
            int r = s >> 2, cs = (s & 3) * 8;
            *(s8v*)&Bs[r][cs] = ld8(fcw, (size_t)(n0 + r) * 512 + k0 + cs, f32);
        }
        __syncthreads();
        int kq = (lane >> 4) * 8;
        s8v af[4], bfv[4];
        for (int i = 0; i < 4; ++i) af[i]  = *(const s8v*)&As[wm * 64 + i * 16 + (lane & 15)][kq];
        for (int i = 0; i < 4; ++i) bfv[i] = *(const s8v*)&Bs[wn * 64 + i * 16 + (lane & 15)][kq];
        for (int mi = 0; mi < 4; ++mi)
            for (int ni = 0; ni < 4; ++ni)
                acc[mi * 4 + ni] = __builtin_amdgcn_mfma_f32_16x16x32_bf16(af[mi], bfv[ni], acc[mi * 4 + ni], 0, 0, 0);
        __syncthreads();
    }
    int n = lane & 15, quad = lane >> 4;
    for (int ni = 0; ni < 4; ++ni) {
        int col = n0 + wn * 64 + ni * 16 + n;
        float bias = ldf(fcb, col, f32);
        for (int mi = 0; mi < 4; ++mi) {
            f4v a = acc[mi * 4 + ni];
            for (int rg = 0; rg < 4; ++rg) {
                int row = m0 + wm * 64 + mi * 16 + quad * 4 + rg;
                float v = a[rg] + bias;
                if (f32) ((float*)out)[(size_t)row * V_ + col] = v;
                else     ((bf16*)out)[(size_t)row * V_ + col] = (bf16)v;
            }
        }
    }
}

extern "C" void kernel_launch(void* const* d_in, const int* in_sizes, int n_in,
                              void* d_out, int out_size, void* d_ws, size_t ws_size,
                              hipStream_t stream) {
    const void* features = d_in[0];
    const int*  captions = (const int*)d_in[1];
    const void* enc      = d_in[3];
    const void* embed    = d_in[4];
    const void* ft1w     = d_in[5];
    const void* ft1b     = d_in[6];
    const void* ft2w     = d_in[7];
    const void* ft2b     = d_in[8];
    const void* w_ih0    = d_in[9];
    const void* w_hh0    = d_in[10];
    const void* b_ih0    = d_in[11];
    const void* b_hh0    = d_in[12];
    const void* w_ih1    = d_in[13];
    const void* w_hh1    = d_in[14];
    const void* b_ih1    = d_in[15];
    const void* b_hh1    = d_in[16];
    const void* fcw      = d_in[17];
    const void* fcb      = d_in[18];

    char* ws = (char*)d_ws;
    size_t off = 0;
    float* t1    = (float*)(ws + off); off += 32 * 512 * 4;
    float* c0    = (float*)(ws + off); off += 32 * 512 * 4;
    float* c1    = (float*)(ws + off); off += 32 * 512 * 4;
    u32* h0A     = (u32*)(ws + off); off += 32 * 512 * 4;
    u32* h0B     = (u32*)(ws + off); off += 32 * 512 * 4;
    u32* h1A     = (u32*)(ws + off); off += 32 * 512 * 4;
    u32* h1B     = (u32*)(ws + off); off += 32 * 512 * 4;
    u32* ctxp    = (u32*)(ws + off); off += 32 * 512 * 4;
    bf16* hs     = (bf16*)(ws + off); off += (size_t)2048 * 512 * 2;
    bf16* enc16  = (bf16*)(ws + off); off += (size_t)32 * 196 * 512 * 2;
    bf16* Wp0    = (bf16*)(ws + off); off += (size_t)2048 * 1024 * 2;
    bf16* Wp1    = (bf16*)(ws + off); off += (size_t)2048 * 1024 * 2;
    float* bias0 = (float*)(ws + off); off += 2048 * 4;
    float* bias1 = (float*)(ws + off); off += 2048 * 4;
    float* Gemb  = (float*)(ws + off); off += (size_t)2048 * 2048 * 4;
    int* dflag   = (int*)(ws + off); off += 16;
    u32* slots   = (u32*)(ws + off); off += NBLK * SLOTSTRIDE * 4;

    k_detect<<<1, 256, 0, stream>>>(features, dflag);
    k_prep<<<1024, 256, 0, stream>>>(dflag, enc, w_ih0, w_hh0, w_ih1, w_hh1,
                                     b_ih0, b_hh0, b_ih1, b_hh1,
                                     enc16, Wp0, Wp1, bias0, bias1, slots);
    k_gemb<<<dim3(16, 32), 256, 0, stream>>>(dflag, captions, embed, w_ih0, Gemb);
    k_feat1<<<4096, 256, 0, stream>>>(dflag, features, ft1w, ft1b, t1);
    k_feat2<<<4096, 256, 0, stream>>>(dflag, t1, ft2w, ft2b, c0, c1, h0A, h1A);
    k_recur<<<NBLK, 256, 0, stream>>>(enc16, Wp0, Wp1, bias0, bias1, Gemb,
                                      c0, c1, h0A, h0B, h1A, h1B, ctxp, hs, slots);
    k_vocab<<<dim3(16, 250), 256, 0, stream>>>(dflag, hs, fcw, fcb, (void*)d_out);
}

// Round 5
// 2387.697 us; speedup vs baseline: 1.9103x; 1.1038x over previous
//
#include <hip/hip_runtime.h>
#include <hip/hip_bf16.h>

typedef __hip_bfloat16 bf16;
typedef short s8v __attribute__((ext_vector_type(8)));   // 8 bf16 payload for MFMA
typedef float f4v __attribute__((ext_vector_type(4)));   // MFMA accumulator
typedef unsigned long long u64;
typedef unsigned int u32;
typedef u32 u32x4v __attribute__((ext_vector_type(4)));  // 16B coherent-load payload

#define B_   32
#define L_   64
#define TENC 196
#define INP  2048
#define H_   512
#define V_   32000
#define NBLK 128   // persistent grid: 128 blocks, 1/CU (LDS-bound), co-resident
#define SLOTSTRIDE 16   // u32s => 64B per slot, one cacheline per block

static __device__ __forceinline__ float sigf(float x) { return 1.0f / (1.0f + expf(-x)); }
static __device__ __forceinline__ short f2bs(float x) {
    bf16 h = (bf16)x;
    return *(short*)&h;
}
static __device__ __forceinline__ float b2f(short s) {
    return __uint_as_float(((unsigned int)(unsigned short)s) << 16);
}
// pack f32 -> (hi bf16 << 16) | lo bf16   (hi+lo reconstructs ~f32 precision)
static __device__ __forceinline__ u32 packhl(float v) {
    bf16 hi = (bf16)v;
    float r = v - (float)hi;
    bf16 lo = (bf16)r;
    return ((u32)(*(unsigned short*)&hi) << 16) | (u32)(*(unsigned short*)&lo);
}
static __device__ __forceinline__ float ldf(const void* p, size_t i, int f32) {
    if (f32) return ((const float*)p)[i];
    return (float)((const bf16*)p)[i];
}
static __device__ __forceinline__ s8v ld8(const void* p, size_t i, int f32) {
    if (f32) {
        const float* fp = (const float*)p + i;
        float4 a = *(const float4*)fp;
        float4 b = *(const float4*)(fp + 4);
        s8v r;
        r[0] = f2bs(a.x); r[1] = f2bs(a.y); r[2] = f2bs(a.z); r[3] = f2bs(a.w);
        r[4] = f2bs(b.x); r[5] = f2bs(b.y); r[6] = f2bs(b.z); r[7] = f2bs(b.w);
        return r;
    }
    return *(const s8v*)((const bf16*)p + i);
}
static __device__ __forceinline__ s8v ld8lo(const void* p, size_t i, int f32) {
    s8v r = {};
    if (f32) {
        const float* fp = (const float*)p + i;
        float4 a = *(const float4*)fp;
        float4 b = *(const float4*)(fp + 4);
        float v[8] = {a.x, a.y, a.z, a.w, b.x, b.y, b.z, b.w};
        for (int j = 0; j < 8; ++j) {
            bf16 hi = (bf16)v[j];
            bf16 lo = (bf16)(v[j] - (float)hi);
            r[j] = *(short*)&lo;
        }
    }
    return r;
}

// ---- device-coherent (agent-scope) access ----
static __device__ __forceinline__ u64 ld64coh(const void* p) {
    return __hip_atomic_load((const u64*)p, __ATOMIC_RELAXED, __HIP_MEMORY_SCOPE_AGENT);
}
static __device__ __forceinline__ void st32coh(u32* p, u32 v) {
    __hip_atomic_store(p, v, __ATOMIC_RELAXED, __HIP_MEMORY_SCOPE_AGENT);
}
static __device__ __forceinline__ void st64coh(u32* p, u64 v) {
    __hip_atomic_store((u64*)p, v, __ATOMIC_RELAXED, __HIP_MEMORY_SCOPE_AGENT);
}

// ---- 16B cache-bypassing (sc0 sc1) load burst: 16 requests/thread for one
// 64KB exchange (vs 32x8B before). Issue all, then waitvm() before use.
// sched_barrier(0) after the waitcnt is MANDATORY (compiler hoists register
// consumers past inline-asm waitcnt otherwise).
static __device__ __forceinline__ void issue16(const u32* St, int tid, u32x4v* f) {
    int b0 = (tid >> 7), k = (tid & 127) * 4;
    #pragma unroll
    for (int q = 0; q < 16; ++q) {
        const u32* s = St + (2 * q + b0) * H_ + k;
        asm volatile("global_load_dwordx4 %0, %1, off sc0 sc1"
                     : "=v"(f[q]) : "v"(s));
    }
}
static __device__ __forceinline__ void waitvm() {
    asm volatile("s_waitcnt vmcnt(0)" ::: "memory");
    __builtin_amdgcn_sched_barrier(0);
}
// unpack hi/lo and write the K-half into Asm (hi row 2b, lo row 2b+1)
static __device__ __forceinline__ void stage16(const u32x4v* f, int tid, short (*A)[520]) {
    int b0 = (tid >> 7), k = (tid & 127) * 4;
    #pragma unroll
    for (int q = 0; q < 16; ++q) {
        u32 v0 = f[q][0], v1 = f[q][1], v2 = f[q][2], v3 = f[q][3];
        int b = 2 * q + b0;
        uint2 hi, lo;
        hi.x = (v0 >> 16) | (v1 & 0xffff0000u);
        hi.y = (v2 >> 16) | (v3 & 0xffff0000u);
        lo.x = (v0 & 0xffffu) | (v1 << 16);
        lo.y = (v2 & 0xffffu) | (v3 << 16);
        *(uint2*)&A[2 * b][k]     = hi;
        *(uint2*)&A[2 * b + 1][k] = lo;
    }
}

// ---- store-slot grid barrier (round 4, kept): arrival = one relaxed store to
// a private slot; wait = per-thread slot poll + __syncthreads_and. Monotone.
static __device__ __forceinline__ void slot_arrive(u32* slots, int blk, u32 val) {
    asm volatile("s_waitcnt vmcnt(0)" ::: "memory");
    __syncthreads();
    if (threadIdx.x == 0)
        __hip_atomic_store(slots + blk * SLOTSTRIDE, val, __ATOMIC_RELAXED, __HIP_MEMORY_SCOPE_AGENT);
}
static __device__ __forceinline__ void slot_wait(const u32* slots, int nslots, u32 val) {
    int tid = threadIdx.x;
    for (;;) {
        u32 v = val;
        if (tid < nslots)
            v = __hip_atomic_load(slots + tid * SLOTSTRIDE, __ATOMIC_RELAXED, __HIP_MEMORY_SCOPE_AGENT);
        if (__syncthreads_and((int)(v >= val))) break;
        __builtin_amdgcn_s_sleep(1);
    }
}

// one K-half of the cell GEMM: A[64 rows] x W[16 gate-rows], K=512
static __device__ __forceinline__ f4v mfma_half(const short (*W)[1048], const short (*A)[520],
                                                int mrow, int nlo, int kq, int koff, f4v acc) {
    #pragma unroll
    for (int kk = 0; kk < 16; ++kk) {
        s8v a = *(const s8v*)&A[mrow][kk * 32 + kq];
        s8v b = *(const s8v*)&W[nlo][koff + kk * 32 + kq];
        acc = __builtin_amdgcn_mfma_f32_16x16x32_bf16(a, b, acc, 0, 0, 0);
    }
    return acc;
}

// ---------------- dtype detector ----------------
__global__ __launch_bounds__(256) void k_detect(const void* __restrict__ feat,
                                                int* __restrict__ flag) {
    __shared__ float red[256];
    const unsigned short* p = (const unsigned short*)feat;
    float mx = 0.f;
    for (int i = threadIdx.x; i < 65536; i += 256) {
        unsigned int u = ((unsigned int)p[i]) << 16;
        float v = __uint_as_float(u);
        mx = fmaxf(mx, fabsf(v));
    }
    red[threadIdx.x] = mx;
    __syncthreads();
    for (int s = 128; s; s >>= 1) {
        if (threadIdx.x < s) red[threadIdx.x] = fmaxf(red[threadIdx.x], red[threadIdx.x + s]);
        __syncthreads();
    }
    if (threadIdx.x == 0) flag[0] = (red[0] > 1e4f) ? 1 : 0;
}

// ---------------- pre-convert enc + LSTM weights to bf16; combine biases; zero slots
__global__ __launch_bounds__(256) void k_prep(const int* __restrict__ dflag,
                                              const void* __restrict__ enc,
                                              const void* __restrict__ w_ih0, const void* __restrict__ w_hh0,
                                              const void* __restrict__ w_ih1, const void* __restrict__ w_hh1,
                                              const void* __restrict__ b_ih0, const void* __restrict__ b_hh0,
                                              const void* __restrict__ b_ih1, const void* __restrict__ b_hh1,
                                              bf16* __restrict__ enc16,
                                              bf16* __restrict__ Wp0, bf16* __restrict__ Wp1,
                                              float* __restrict__ bias0, float* __restrict__ bias1,
                                              u32* __restrict__ slots) {
    int f32 = *dflag;
    int gid = blockIdx.x * 256 + threadIdx.x;
    if (gid < NBLK * SLOTSTRIDE) slots[gid] = 0;
    const int GE = (B_ * TENC * H_) / 8;      // 401408
    const int GW = (2048 * 1024) / 8;         // 262144
    int stride = gridDim.x * 256;
    for (int g = gid; g < GE + 2 * GW; g += stride) {
        if (g < GE) {
            *(s8v*)(enc16 + (size_t)g * 8) = ld8(enc, (size_t)g * 8, f32);
        } else if (g < GE + GW) {
            int gg = g - GE; int j = gg >> 7; int k = (gg & 127) * 8;
            s8v v = (k < 512) ? ld8(w_ih0, (size_t)j * 1024 + 512 + k, f32)
                              : ld8(w_hh0, (size_t)j * 512 + (k - 512), f32);
            *(s8v*)(Wp0 + (size_t)j * 1024 + k) = v;
        } else {
            int gg = g - GE - GW; int j = gg >> 7; int k = (gg & 127) * 8;
            s8v v = (k < 512) ? ld8(w_ih1, (size_t)j * 512 + k, f32)
                              : ld8(w_hh1, (size_t)j * 512 + (k - 512), f32);
            *(s8v*)(Wp1 + (size_t)j * 1024 + k) = v;
        }
    }
    for (int j = gid; j < 2048; j += stride) {
        bias0[j] = ldf(b_ih0, j, f32) + ldf(b_hh0, j, f32);
        bias1[j] = ldf(b_ih1, j, f32) + ldf(b_hh1, j, f32);
    }
}

// ---------------- Gemb[t*32+b][j] = emb(hi/lo) @ w_ih0[:, 0:512]^T  (f32 out) --------
__global__ __launch_bounds__(256) void k_gemb(const int* __restrict__ dflag,
                                              const int* __restrict__ captions,
                                              const void* __restrict__ embed,
                                              const void* __restrict__ w_ih0,
                                              float* __restrict__ Gemb) {
    __shared__ short As[128][40];
    __shared__ short Bs[128][40];
    int f32 = *dflag;
    int n0 = blockIdx.x * 128;
    int m0 = blockIdx.y * 128;
    int tid = threadIdx.x, lane = tid & 63, wv = tid >> 6;
    int wm = wv >> 1, wn = wv & 1;
    f4v acc[16] = {};
    for (int k0 = 0; k0 < 512; k0 += 32) {
        for (int s = tid; s < 512; s += 256) {
            int r = s >> 2, cs = (s & 3) * 8;
            int R = m0 + r, e = R >> 1, part = R & 1;
            int b = e & 31, tt = e >> 5;
            size_t ei = (size_t)captions[b * L_ + tt] * H_ + k0 + cs;
            *(s8v*)&As[r][cs] = part ? ld8lo(embed, ei, f32) : ld8(embed, ei, f32);
        }
        for (int s = tid; s < 512; s += 256) {
            int r = s >> 2, cs = (s & 3) * 8;
            *(s8v*)&Bs[r][cs] = ld8(w_ih0, (size_t)(n0 + r) * 1024 + k0 + cs, f32);
        }
        __syncthreads();
        int kq = (lane >> 4) * 8;
        s8v af[4], bfv[4];
        for (int i = 0; i < 4; ++i) af[i]  = *(const s8v*)&As[wm * 64 + i * 16 + (lane & 15)][kq];
        for (int i = 0; i < 4; ++i) bfv[i] = *(const s8v*)&Bs[wn * 64 + i * 16 + (lane & 15)][kq];
        for (int mi = 0; mi < 4; ++mi)
            for (int ni = 0; ni < 4; ++ni)
                acc[mi * 4 + ni] = __builtin_amdgcn_mfma_f32_16x16x32_bf16(af[mi], bfv[ni], acc[mi * 4 + ni], 0, 0, 0);
        __syncthreads();
    }
    int n = lane & 15, quad = lane >> 4;
    for (int ni = 0; ni < 4; ++ni) {
        int col = n0 + wn * 64 + ni * 16 + n;
        for (int mi = 0; mi < 4; ++mi) {
            f4v a = acc[mi * 4 + ni];
            int rowbase = m0 + wm * 64 + mi * 16 + quad * 4;
            int e0 = rowbase >> 1;
            Gemb[(size_t)e0 * 2048 + col]       = a[0] + a[1];
            Gemb[(size_t)(e0 + 1) * 2048 + col] = a[2] + a[3];
        }
    }
}

// ---------------- feature MLP ----------------
__global__ __launch_bounds__(256) void k_feat1(const int* __restrict__ dflag,
                                               const void* __restrict__ feat,
                                               const void* __restrict__ w,
                                               const void* __restrict__ bias,
                                               float* __restrict__ t1) {
    int f32 = *dflag;
    int wid = (blockIdx.x * 256 + threadIdx.x) >> 6;
    int lane = threadIdx.x & 63;
    int b = wid >> 9, o = wid & 511;
    float acc = 0.f;
    for (int k = lane; k < INP; k += 64)
        acc += ldf(feat, (size_t)b * INP + k, f32) * ldf(w, (size_t)o * INP + k, f32);
    for (int off = 32; off; off >>= 1) acc += __shfl_down(acc, off, 64);
    if (lane == 0) {
        acc += ldf(bias, o, f32);
        t1[b * H_ + o] = acc > 0.f ? acc : 0.f;
    }
}

__global__ __launch_bounds__(256) void k_feat2(const int* __restrict__ dflag,
                                               const float* __restrict__ t1,
                                               const void* __restrict__ w,
                                               const void* __restrict__ bias,
                                               float* __restrict__ c0, float* __restrict__ c1,
                                               u32* __restrict__ h0A, u32* __restrict__ h1A) {
    int f32 = *dflag;
    int wid = (blockIdx.x * 256 + threadIdx.x) >> 6;
    int lane = threadIdx.x & 63;
    int b = wid >> 9, o = wid & 511;
    float acc = 0.f;
    for (int k = lane; k < H_; k += 64)
        acc += t1[b * H_ + k] * ldf(w, (size_t)o * H_ + k, f32);
    for (int off = 32; off; off >>= 1) acc += __shfl_down(acc, off, 64);
    if (lane == 0) {
        float v = acc + ldf(bias, o, f32);
        int idx = b * H_ + o;
        c0[idx] = v; c1[idx] = v;
        u32 pk = packhl(v);
        h0A[idx] = pk; h1A[idx] = pk;
    }
}

// ---------------- persistent recurrence kernel ----------------
// 128 blocks x 4 units. Weights LDS-resident. Asm RETAINS staged h0(t-1)
// across the step boundary (phase C stages it; phase A reuses it) -> only 3
// coherent exchange-reads per step (h1prev, ctx, h0new), each 16 x 16B/thread.
//   A: [blk<32: attention, ctx store, arrive] ; all: MFMA h0-half (retained Asm),
//      exchange h1prev + MFMA h1-half ; wait barA (32 producers)
//   B: exchange ctx, MFMA, epilogue0 -> h0new | barB (full)
//   C: exchange h0new, MFMA, epilogue1 -> h1new, hs (Asm kept for next A) | barC
__global__ __launch_bounds__(256, 1) void k_recur(
        const bf16* __restrict__ enc16,
        const bf16* __restrict__ Wp0, const bf16* __restrict__ Wp1,
        const float* __restrict__ bias0, const float* __restrict__ bias1,
        const float* __restrict__ Gemb,
        const float* __restrict__ c0i, const float* __restrict__ c1i,
        u32* __restrict__ h0A, u32* __restrict__ h0B,
        u32* __restrict__ h1A, u32* __restrict__ h1B,
        u32* __restrict__ ctxp,
        bf16* __restrict__ hs, u32* __restrict__ slots) {
    __shared__ short Asm[64][520];        // 66.5 KB: A-half [32b x hi/lo][512k]
    __shared__ short Wsm[2][16][1048];    // 67.1 KB: resident weights, 2 cells
    __shared__ float qs[H_];
    __shared__ float sc[256];
    __shared__ float wred[8];
    __shared__ float ep[4][4][32];
    const float SCALE = 0.04419417382415922f;
    int blk = blockIdx.x, tid = threadIdx.x;
    int lane = tid & 63, wv = tid >> 6;
    int u0 = blk * 4;                      // 4 hidden units per block
    int mrow = wv * 16 + (lane & 15);
    int kq = (lane >> 4) * 8;
    int nlo = lane & 15;
    int quad = lane >> 4;
    int b0i = wv * 8 + quad * 2;
    int eb = tid & 31, eu = (tid >> 5) & 3, ej = u0 + eu;
    int epi = tid < 128;

    // resident weight load (once)
    for (int cell = 0; cell < 2; ++cell) {
        const bf16* Wp = cell ? Wp1 : Wp0;
        for (int s = tid; s < 2048; s += 256) {
            int r = s >> 7, cc = (s & 127) * 8;
            size_t j = (size_t)((r >> 2) * H_ + u0 + (r & 3));
            *(s8v*)&Wsm[cell][r][cc] = *(const s8v*)(Wp + j * 1024 + cc);
        }
    }
    float c0r = 0.f, c1r = 0.f;
    float bi0 = 0, bf0 = 0, bg0 = 0, bo0 = 0, bi1 = 0, bf1 = 0, bg1 = 0, bo1 = 0;
    if (epi) {
        c0r = c0i[eb * H_ + ej]; c1r = c1i[eb * H_ + ej];
        bi0 = bias0[ej]; bf0 = bias0[512 + ej]; bg0 = bias0[1024 + ej]; bo0 = bias0[1536 + ej];
        bi1 = bias1[ej]; bf1 = bias1[512 + ej]; bg1 = bias1[1024 + ej]; bo1 = bias1[1536 + ej];
    }
    // prologue: stage h0(t=0) into Asm (retained-Asm invariant entry)
    {
        u32x4v f0[16];
        issue16(h0A, tid, f0);
        waitvm();
        stage16(f0, tid, Asm);
    }
    __syncthreads();
    u32 nbar = 0;

    for (int t = 0; t < L_; ++t) {
        int p = t & 1;
        u32* h0n = p ? h0A : h0B;
        const u32* h1p = p ? h1B : h1A;  u32* h1n = p ? h1A : h1B;

        // ===== Phase A =====
        u32 barA = ++nbar;
        if (blk < B_) {
            int b = blk;
            {
                u64 v = ld64coh(h1p + b * H_ + 2 * tid);
                u32 v0 = (u32)v, v1 = (u32)(v >> 32);
                qs[2 * tid]     = b2f((short)(v0 >> 16)) + b2f((short)(v0 & 0xffffu));
                qs[2 * tid + 1] = b2f((short)(v1 >> 16)) + b2f((short)(v1 & 0xffffu));
            }
            __syncthreads();
            if (tid < TENC) {
                const bf16* erow = enc16 + ((size_t)b * TENC + tid) * H_;
                float a0 = 0, a1 = 0, a2 = 0, a3 = 0, a4 = 0, a5 = 0, a6 = 0, a7 = 0;
                #pragma unroll 4
                for (int k = 0; k < H_; k += 8) {
                    s8v e8 = *(const s8v*)(erow + k);
                    float4 q0 = *(const float4*)&qs[k];
                    float4 q1 = *(const float4*)&qs[k + 4];
                    a0 += q0.x * b2f(e8[0]); a1 += q0.y * b2f(e8[1]);
                    a2 += q0.z * b2f(e8[2]); a3 += q0.w * b2f(e8[3]);
                    a4 += q1.x * b2f(e8[4]); a5 += q1.y * b2f(e8[5]);
                    a6 += q1.z * b2f(e8[6]); a7 += q1.w * b2f(e8[7]);
                }
                sc[tid] = (((a0 + a1) + (a2 + a3)) + ((a4 + a5) + (a6 + a7))) * SCALE;
            }
            __syncthreads();
            float v = (tid < TENC) ? sc[tid] : -1e30f;
            float m = v;
            #pragma unroll
            for (int off = 32; off; off >>= 1) m = fmaxf(m, __shfl_xor(m, off, 64));
            if (lane == 0) wred[wv] = m;
            __syncthreads();
            m = fmaxf(fmaxf(wred[0], wred[1]), fmaxf(wred[2], wred[3]));
            float e = (tid < TENC) ? expf(v - m) : 0.f;
            float s = e;
            #pragma unroll
            for (int off = 32; off; off >>= 1) s += __shfl_xor(s, off, 64);
            if (lane == 0) wred[4 + wv] = s;
            __syncthreads();
            float inv = 1.0f / ((wred[4] + wred[5]) + (wred[6] + wred[7]));
            if (tid < TENC) sc[tid] = e * inv;
            __syncthreads();
            const bf16* ebase = enc16 + (size_t)b * TENC * H_ + 2 * tid;
            float x0 = 0, x1 = 0, y0 = 0, y1 = 0;
            #pragma unroll 4
            for (int tt = 0; tt < TENC; tt += 2) {
                u32 ua = *(const u32*)(ebase + (size_t)tt * H_);
                u32 ub = *(const u32*)(ebase + (size_t)(tt + 1) * H_);
                float p0 = sc[tt], p1 = sc[tt + 1];
                x0 += p0 * b2f((short)ua); x1 += p0 * b2f((short)(ua >> 16));
                y0 += p1 * b2f((short)ub); y1 += p1 * b2f((short)(ub >> 16));
            }
            u64 pk = ((u64)packhl(x1 + y1) << 32) | (u64)packhl(x0 + y0);
            st64coh(ctxp + b * H_ + 2 * tid, pk);
            slot_arrive(slots, blk, barA);       // arrive EARLY (split barrier)
        }
        // local work (all blocks): cell0 h0prev-half from RETAINED Asm
        f4v accB = {};
        accB = mfma_half(Wsm[0], Asm, mrow, nlo, kq, 512, accB);
        __syncthreads();                         // Asm reads done before overwrite
        f4v accC = {};
        {
            u32x4v fC[16];
            issue16(h1p, tid, fC);               // h1prev exchange (published barC t-1)
            waitvm();
            stage16(fC, tid, Asm);
            __syncthreads();
            accC = mfma_half(Wsm[1], Asm, mrow, nlo, kq, 512, accC);
        }
        slot_wait(slots, B_, barA);              // wait LATE

        // ===== Phase B: ctx half of cell0 + epilogue0 -> h0new =====
        u32 barB = ++nbar;
        {
            u32x4v fB[16];
            issue16(ctxp, tid, fB);              // fresh (just produced)
            float g0 = 0, g1 = 0, g2 = 0, g3 = 0;
            if (epi) {
                size_t ge = (size_t)(t * 32 + eb) * 2048 + ej;
                g0 = Gemb[ge]; g1 = Gemb[ge + 512]; g2 = Gemb[ge + 1024]; g3 = Gemb[ge + 1536];
            }
            waitvm();
            stage16(fB, tid, Asm);
            __syncthreads();
            accB = mfma_half(Wsm[0], Asm, mrow, nlo, kq, 0, accB);
            ep[nlo >> 2][nlo & 3][b0i]     = accB[0] + accB[1];
            ep[nlo >> 2][nlo & 3][b0i + 1] = accB[2] + accB[3];
            __syncthreads();
            if (epi) {
                float gi = ep[0][eu][eb] + bi0 + g0;
                float gf = ep[1][eu][eb] + bf0 + g1;
                float gg = ep[2][eu][eb] + bg0 + g2;
                float go = ep[3][eu][eb] + bo0 + g3;
                float c2 = sigf(gf) * c0r + sigf(gi) * tanhf(gg);
                float h2 = sigf(go) * tanhf(c2);
                c0r = c2;
                st32coh(h0n + eb * H_ + ej, packhl(h2));
            }
            slot_arrive(slots, blk, barB);
            slot_wait(slots, NBLK, barB);
        }

        // ===== Phase C: h0new half of cell1 + epilogue1 (Asm kept for next A) =====
        u32 barC = ++nbar;
        {
            u32x4v fD[16];
            issue16(h0n, tid, fD);
            waitvm();
            stage16(fD, tid, Asm);
            __syncthreads();
            accC = mfma_half(Wsm[1], Asm, mrow, nlo, kq, 0, accC);
            ep[nlo >> 2][nlo & 3][b0i]     = accC[0] + accC[1];
            ep[nlo >> 2][nlo & 3][b0i + 1] = accC[2] + accC[3];
            __syncthreads();
            if (epi) {
                float gi = ep[0][eu][eb] + bi1;
                float gf = ep[1][eu][eb] + bf1;
                float gg = ep[2][eu][eb] + bg1;
                float go = ep[3][eu][eb] + bo1;
                float c2 = sigf(gf) * c1r + sigf(gi) * tanhf(gg);
                float h2 = sigf(go) * tanhf(c2);
                c1r = c2;
                st32coh(h1n + eb * H_ + ej, packhl(h2));
                hs[(size_t)(t * 32 + eb) * H_ + ej] = (bf16)h2;
            }
            slot_arrive(slots, blk, barC);
            slot_wait(slots, NBLK, barC);
        }
        // Asm now holds staged h0(t) == h0prev for step t+1 (retained).
    }
}

// ---------------- vocab projection (grid transposed: m fastest for fcw reuse) -------
__global__ __launch_bounds__(256) void k_vocab(const int* __restrict__ dflag,
                                               const bf16* __restrict__ hs,
                                               const void* __restrict__ fcw,
                                               const void* __restrict__ fcb,
                                               void* __restrict__ out) {
    __shared__ short As[128][40];
    __shared__ short Bs[128][40];
    int f32 = *dflag;
    int m0 = blockIdx.x * 128;
    int n0 = blockIdx.y * 128;
    int tid = threadIdx.x, lane = tid & 63, wv = tid >> 6;
    int wm = wv >> 1, wn = wv & 1;
    f4v acc[16] = {};
    for (int k0 = 0; k0 < 512; k0 += 32) {
        for (int s = tid; s < 512; s += 256) {
            int r = s >> 2, cs = (s & 3) * 8;
            *(s8v*)&As[r][cs] = *(const s8v*)(hs + (size_t)(m0 + r) * 512 + k0 + cs);
        }
        for (int s = tid; s < 512; s += 256) {
            int r = s >> 2, cs = (s & 3) * 8;
            *(s8v*)&Bs[r][cs] = ld8(fcw, (size_t)(n0 + r) * 512 + k0 + cs, f32);
        }
        __syncthreads();
        int kq = (lane >> 4) * 8;
        s8v af[4], bfv[4];
        for (int i = 0; i < 4; ++i) af[i]  = *(const s8v*)&As[wm * 64 + i * 16 + (lane & 15)][kq];
        for (int i = 0; i < 4; ++i) bfv[i] = *(const s8v*)&Bs[wn * 64 + i * 16 + (lane & 15)][kq];
        for (int mi = 0; mi < 4; ++mi)
            for (int ni = 0; ni < 4; ++ni)
                acc[mi * 4 + ni] = __builtin_amdgcn_mfma_f32_16x16x32_bf16(af[mi], bfv[ni], acc[mi * 4 + ni], 0, 0, 0);
        __syncthreads();
    }
    int n = lane & 15, quad = lane >> 4;
    for (int ni = 0; ni < 4; ++ni) {
        int col = n0 + wn * 64 + ni * 16 + n;
        float bias = ldf(fcb, col, f32);
        for (int mi = 0; mi < 4; ++mi) {
            f4v a = acc[mi * 4 + ni];
            for (int rg = 0; rg < 4; ++rg) {
                int row = m0 + wm * 64 + mi * 16 + quad * 4 + rg;
                float v = a[rg] + bias;
                if (f32) ((float*)out)[(size_t)row * V_ + col] = v;
                else     ((bf16*)out)[(size_t)row * V_ + col] = (bf16)v;
            }
        }
    }
}

extern "C" void kernel_launch(void* const* d_in, const int* in_sizes, int n_in,
                              void* d_out, int out_size, void* d_ws, size_t ws_size,
                              hipStream_t stream) {
    const void* features = d_in[0];
    const int*  captions = (const int*)d_in[1];
    const void* enc      = d_in[3];
    const void* embed    = d_in[4];
    const void* ft1w     = d_in[5];
    const void* ft1b     = d_in[6];
    const void* ft2w     = d_in[7];
    const void* ft2b     = d_in[8];
    const void* w_ih0    = d_in[9];
    const void* w_hh0    = d_in[10];
    const void* b_ih0    = d_in[11];
    const void* b_hh0    = d_in[12];
    const void* w_ih1    = d_in[13];
    const void* w_hh1    = d_in[14];
    const void* b_ih1    = d_in[15];
    const void* b_hh1    = d_in[16];
    const void* fcw      = d_in[17];
    const void* fcb      = d_in[18];

    char* ws = (char*)d_ws;
    size_t off = 0;
    float* t1    = (float*)(ws + off); off += 32 * 512 * 4;
    float* c0    = (float*)(ws + off); off += 32 * 512 * 4;
    float* c1    = (float*)(ws + off); off += 32 * 512 * 4;
    u32* h0A     = (u32*)(ws + off); off += 32 * 512 * 4;
    u32* h0B     = (u32*)(ws + off); off += 32 * 512 * 4;
    u32* h1A     = (u32*)(ws + off); off += 32 * 512 * 4;
    u32* h1B     = (u32*)(ws + off); off += 32 * 512 * 4;
    u32* ctxp    = (u32*)(ws + off); off += 32 * 512 * 4;
    bf16* hs     = (bf16*)(ws + off); off += (size_t)2048 * 512 * 2;
    bf16* enc16  = (bf16*)(ws + off); off += (size_t)32 * 196 * 512 * 2;
    bf16* Wp0    = (bf16*)(ws + off); off += (size_t)2048 * 1024 * 2;
    bf16* Wp1    = (bf16*)(ws + off); off += (size_t)2048 * 1024 * 2;
    float* bias0 = (float*)(ws + off); off += 2048 * 4;
    float* bias1 = (float*)(ws + off); off += 2048 * 4;
    float* Gemb  = (float*)(ws + off); off += (size_t)2048 * 2048 * 4;
    int* dflag   = (int*)(ws + off); off += 16;
    u32* slots   = (u32*)(ws + off); off += NBLK * SLOTSTRIDE * 4;

    k_detect<<<1, 256, 0, stream>>>(features, dflag);
    k_prep<<<1024, 256, 0, stream>>>(dflag, enc, w_ih0, w_hh0, w_ih1, w_hh1,
                                     b_ih0, b_hh0, b_ih1, b_hh1,
                                     enc16, Wp0, Wp1, bias0, bias1, slots);
    k_gemb<<<dim3(16, 32), 256, 0, stream>>>(dflag, captions, embed, w_ih0, Gemb);
    k_feat1<<<4096, 256, 0, stream>>>(dflag, features, ft1w, ft1b, t1);
    k_feat2<<<4096, 256, 0, stream>>>(dflag, t1, ft2w, ft2b, c0, c1, h0A, h1A);
    k_recur<<<NBLK, 256, 0, stream>>>(enc16, Wp0, Wp1, bias0, bias1, Gemb,
                                      c0, c1, h0A, h0B, h1A, h1B, ctxp, hs, slots);
    k_vocab<<<dim3(16, 250), 256, 0, stream>>>(dflag, hs, fcw, fcb, (void*)d_out);
}